// Round 1
// baseline (9628.396 us; speedup 1.0000x reference)
//
#include <hip/hip_runtime.h>
#include <cstddef>

// Problem constants
#define BATCH 8
#define LSEQ 1024
#define DMODEL 512
#define DINNER 1024
#define DSTATE 16
#define DTRANK 32
#define NHEAD 8
#define DHEAD 64
#define DFF 2048
#define MTOK 8192   // BATCH*LSEQ

__device__ __forceinline__ float wave_max(float v) {
#pragma unroll
  for (int o = 32; o; o >>= 1) v = fmaxf(v, __shfl_xor(v, o));
  return v;
}
__device__ __forceinline__ float wave_sum(float v) {
#pragma unroll
  for (int o = 32; o; o >>= 1) v += __shfl_xor(v, o);
  return v;
}
__device__ __forceinline__ float silu_f(float x) { return x / (1.f + __expf(-x)); }

// ---------------------------------------------------------------------------
// Input projection: h[b,l,d] = sum_c x[b,c,l] * pw[d,c] + pb[d]
// ---------------------------------------------------------------------------
__global__ __launch_bounds__(256) void proj_kernel(const float* __restrict__ x,
                                                   const float* __restrict__ pw,
                                                   const float* __restrict__ pb,
                                                   float* __restrict__ h) {
  int idx = blockIdx.x * 256 + threadIdx.x;        // ((b*L)+l)*512 + d
  int d = idx & 511;
  int l = (idx >> 9) & 1023;
  int b = idx >> 19;
  const float* xb = x + (size_t)b * 3 * 1024 + l;
  h[idx] = pb[d] + xb[0] * pw[d * 3] + xb[1024] * pw[d * 3 + 1] + xb[2048] * pw[d * 3 + 2];
}

// ---------------------------------------------------------------------------
// Generic tiled SGEMM: C[m,n] = act( sum_k A[m,k]*W[n,k] + bias[n] )
// A: (M,K) row-major with leading dim lda; W: (N,K) row-major contiguous.
// ACT: 0 none, 1 relu, 2 softplus
// ---------------------------------------------------------------------------
template <int ACT>
__global__ __launch_bounds__(256) void gemm_tn(const float* __restrict__ A,
                                               const float* __restrict__ W,
                                               const float* __restrict__ bias,
                                               float* __restrict__ C,
                                               int M, int N, int K, int lda, int ldc) {
  __shared__ float As[16][65];
  __shared__ float Ws[16][65];
  const int bm = blockIdx.y * 64, bn = blockIdx.x * 64;
  const int tid = threadIdx.x;
  const int lk = tid & 15, lr = tid >> 4;   // loader: k, row-group
  const int tx = tid & 15, ty = tid >> 4;   // compute: n-group, m-group
  float acc[4][4] = {};
  for (int k0 = 0; k0 < K; k0 += 16) {
#pragma unroll
    for (int i = 0; i < 4; ++i) {
      As[lk][lr + 16 * i] = A[(size_t)(bm + lr + 16 * i) * lda + k0 + lk];
      Ws[lk][lr + 16 * i] = W[(size_t)(bn + lr + 16 * i) * K + k0 + lk];
    }
    __syncthreads();
#pragma unroll
    for (int kk = 0; kk < 16; ++kk) {
      float a[4], w[4];
#pragma unroll
      for (int i = 0; i < 4; ++i) a[i] = As[kk][ty + 16 * i];
#pragma unroll
      for (int j = 0; j < 4; ++j) w[j] = Ws[kk][tx + 16 * j];
#pragma unroll
      for (int i = 0; i < 4; ++i)
#pragma unroll
        for (int j = 0; j < 4; ++j) acc[i][j] += a[i] * w[j];
    }
    __syncthreads();
  }
#pragma unroll
  for (int i = 0; i < 4; ++i) {
    int r = bm + ty + 16 * i;
#pragma unroll
    for (int j = 0; j < 4; ++j) {
      int c = bn + tx + 16 * j;
      float v = acc[i][j];
      if (bias) v += bias[c];
      if (ACT == 1) v = fmaxf(v, 0.f);
      if (ACT == 2) v = (v > 20.f) ? v : log1pf(__expf(v));
      C[(size_t)r * ldc + c] = v;
    }
  }
}

// ---------------------------------------------------------------------------
// Depthwise causal conv (width 4) + SiLU.  xm = xz[:, :DINNER] (row stride 2048)
// ---------------------------------------------------------------------------
__global__ __launch_bounds__(256) void conv_silu_kernel(const float* __restrict__ xz,
                                                        const float* __restrict__ cw,
                                                        const float* __restrict__ cb,
                                                        float* __restrict__ xc) {
  int idx = blockIdx.x * 256 + threadIdx.x;        // ((b*L)+t)*1024 + d
  int d = idx & 1023;
  int t = (idx >> 10) & 1023;
  int b = idx >> 20;
  float acc = cb[d];
#pragma unroll
  for (int w = 0; w < 4; ++w) {
    int tt = t - 3 + w;
    if (tt >= 0) acc += xz[(((size_t)(b * 1024 + tt)) << 11) + d] * cw[d * 4 + w];
  }
  xc[idx] = silu_f(acc);
}

// ---------------------------------------------------------------------------
// Selective scan: one thread per (b,d) channel, 16 states in registers.
// Reads dt (B,L,DI), xdb (B,L,64) [B at +32, C at +48], xc (B,L,DI),
// z from xz[...,1024+d]; writes gated y into xz[..., d] (dead xm slot).
// ---------------------------------------------------------------------------
__global__ __launch_bounds__(256) void scan_kernel(const float* __restrict__ dt,
                                                   const float* __restrict__ xdb,
                                                   const float* __restrict__ xc,
                                                   float* __restrict__ xz,
                                                   const float* __restrict__ Alog,
                                                   const float* __restrict__ Dp) {
  int idx = blockIdx.x * 256 + threadIdx.x;        // b*1024 + d
  int b = idx >> 10, d = idx & 1023;
  float A[16], st[16];
#pragma unroll
  for (int s = 0; s < 16; ++s) {
    A[s] = -__expf(Alog[d * 16 + s]);
    st[s] = 0.f;
  }
  float Dv = Dp[d];
  for (int t = 0; t < 1024; ++t) {
    size_t base = (((size_t)(b * 1024 + t)) << 10) + d;
    float dtv = dt[base];
    float xv = xc[base];
    size_t xrow = (size_t)(b * 1024 + t) * 64;
    float dx = dtv * xv;
    float acc = 0.f;
#pragma unroll
    for (int s = 0; s < 16; ++s) {
      st[s] = st[s] * __expf(dtv * A[s]) + dx * xdb[xrow + 32 + s];
      acc += st[s] * xdb[xrow + 48 + s];
    }
    size_t zrow = ((size_t)(b * 1024 + t)) << 11;
    float zv = xz[zrow + 1024 + d];
    xz[zrow + d] = (acc + Dv * xv) * silu_f(zv);
  }
}

// ---------------------------------------------------------------------------
// Residual + LayerNorm (in-place capable). add may be nullptr.
// One block (128 threads) per 512-wide row.
// ---------------------------------------------------------------------------
__global__ __launch_bounds__(128) void resid_ln_kernel(const float* __restrict__ x,
                                                       const float* __restrict__ add,
                                                       const float* __restrict__ w,
                                                       const float* __restrict__ bias,
                                                       float* __restrict__ out) {
  int row = blockIdx.x, tid = threadIdx.x;
  float4 v = ((const float4*)(x + (size_t)row * 512))[tid];
  if (add) {
    float4 a = ((const float4*)(add + (size_t)row * 512))[tid];
    v.x += a.x; v.y += a.y; v.z += a.z; v.w += a.w;
  }
  float s = v.x + v.y + v.z + v.w;
  float ss = v.x * v.x + v.y * v.y + v.z * v.z + v.w * v.w;
#pragma unroll
  for (int o = 32; o; o >>= 1) {
    s += __shfl_xor(s, o);
    ss += __shfl_xor(ss, o);
  }
  __shared__ float red[4];
  int wid = tid >> 6;
  if ((tid & 63) == 0) { red[wid] = s; red[2 + wid] = ss; }
  __syncthreads();
  s = red[0] + red[1];
  ss = red[2] + red[3];
  float mean = s * (1.f / 512.f);
  float var = ss * (1.f / 512.f) - mean * mean;
  float inv = rsqrtf(var + 1e-5f);
  float4 wv = ((const float4*)w)[tid];
  float4 bv = ((const float4*)bias)[tid];
  float4 ov;
  ov.x = (v.x - mean) * inv * wv.x + bv.x;
  ov.y = (v.y - mean) * inv * wv.y + bv.y;
  ov.z = (v.z - mean) * inv * wv.z + bv.z;
  ov.w = (v.w - mean) * inv * wv.w + bv.w;
  ((float4*)(out + (size_t)row * 512))[tid] = ov;
}

// ---------------------------------------------------------------------------
// Sinusoidal positional encoding add (in-place on h)
// ---------------------------------------------------------------------------
__global__ __launch_bounds__(256) void posenc_kernel(float* __restrict__ h) {
  int idx = blockIdx.x * 256 + threadIdx.x;        // ((b*L)+l)*512 + d
  int d = idx & 511;
  int l = (idx >> 9) & 1023;
  float freq = __expf(-(float)(d & ~1) * (9.210340371976184f / 512.f));
  float ang = (float)l * freq;
  h[idx] += (d & 1) ? cosf(ang) : sinf(ang);
}

// ---------------------------------------------------------------------------
// Full (non-causal) attention, one wave per query row, online softmax.
// qkv: (B, L, 1536) with q/k/v at offsets 0/512/1024, heads of 64.
// ao:  (B, L, 512)  [d = h*64+dh]
// ---------------------------------------------------------------------------
__global__ __launch_bounds__(256) void attn_kernel(const float* __restrict__ qkv,
                                                   float* __restrict__ ao) {
  __shared__ float sq[4][64];
  __shared__ float sp[4][64];
  int wid = threadIdx.x >> 6, lane = threadIdx.x & 63;
  int row = blockIdx.x * 4 + wid;                  // b*8192 + h*1024 + l
  int l = row & 1023;
  int hh = (row >> 10) & 7;
  int b = row >> 13;
  const float* qp = qkv + ((size_t)(b * 1024 + l)) * 1536 + hh * 64;
  sq[wid][lane] = qp[lane] * 0.125f;               // 1/sqrt(64)
  const float* kbase = qkv + (size_t)b * 1024 * 1536 + 512 + hh * 64;
  const float* vbase = qkv + (size_t)b * 1024 * 1536 + 1024 + hh * 64;
  float m = -1e30f, lsum = 0.f, o = 0.f;
  for (int j0 = 0; j0 < 1024; j0 += 64) {
    const float* kp = kbase + (size_t)(j0 + lane) * 1536;
    float sdot = 0.f;
#pragma unroll
    for (int d4 = 0; d4 < 64; d4 += 4) {
      float4 kk = *(const float4*)(kp + d4);
      sdot += sq[wid][d4] * kk.x + sq[wid][d4 + 1] * kk.y +
              sq[wid][d4 + 2] * kk.z + sq[wid][d4 + 3] * kk.w;
    }
    float mc = wave_max(sdot);
    float mn = fmaxf(m, mc);
    float alpha = __expf(m - mn);
    float p = __expf(sdot - mn);
    lsum = lsum * alpha + wave_sum(p);
    sp[wid][lane] = p;
    o *= alpha;
    const float* vp = vbase + (size_t)j0 * 1536 + lane;
#pragma unroll 8
    for (int j = 0; j < 64; ++j) o += sp[wid][j] * vp[(size_t)j * 1536];
    m = mn;
  }
  ao[((size_t)(b * 1024 + l)) * 512 + hh * 64 + lane] = o / lsum;
}

// ---------------------------------------------------------------------------
// Mean over L: out2[b,d] = mean_l hout[b,l,d]
// ---------------------------------------------------------------------------
__global__ __launch_bounds__(256) void mean_kernel(const float* __restrict__ hout,
                                                   float* __restrict__ out2) {
  int idx = blockIdx.x * 256 + threadIdx.x;        // b*512 + d
  int b = idx >> 9, d = idx & 511;
  float s = 0.f;
  for (int l = 0; l < 1024; ++l) s += hout[(((size_t)(b * 1024 + l)) << 9) + d];
  out2[idx] = s * (1.f / 1024.f);
}

// ---------------------------------------------------------------------------
extern "C" void kernel_launch(void* const* d_in, const int* in_sizes, int n_in,
                              void* d_out, int out_size, void* d_ws, size_t ws_size,
                              hipStream_t stream) {
  const float* x        = (const float*)d_in[0];
  const float* proj_w   = (const float*)d_in[1];
  const float* proj_b   = (const float*)d_in[2];
  const float* m_in_w   = (const float*)d_in[3];
  const float* m_conv_w = (const float*)d_in[4];
  const float* m_conv_b = (const float*)d_in[5];
  const float* m_xproj_w= (const float*)d_in[6];
  const float* m_dt_w   = (const float*)d_in[7];
  const float* m_dt_b   = (const float*)d_in[8];
  const float* m_Alog   = (const float*)d_in[9];
  const float* m_D      = (const float*)d_in[10];
  const float* m_out_w  = (const float*)d_in[11];
  const float* m_ln_w   = (const float*)d_in[12];
  const float* m_ln_b   = (const float*)d_in[13];
  const float* t_qkv_w  = (const float*)d_in[14];
  const float* t_qkv_b  = (const float*)d_in[15];
  const float* t_ow     = (const float*)d_in[16];
  const float* t_ob     = (const float*)d_in[17];
  const float* t_l1w    = (const float*)d_in[18];
  const float* t_l1b    = (const float*)d_in[19];
  const float* t_l2w    = (const float*)d_in[20];
  const float* t_l2b    = (const float*)d_in[21];
  const float* t_ln1w   = (const float*)d_in[22];
  const float* t_ln1b   = (const float*)d_in[23];
  const float* t_ln2w   = (const float*)d_in[24];
  const float* t_ln2b   = (const float*)d_in[25];
  const float* no_w     = (const float*)d_in[26];
  const float* no_b     = (const float*)d_in[27];

  float* ws   = (float*)d_ws;
  float* h    = ws;                   //  4,194,304 f  (B,L,512)
  float* bufA = h + 4194304;          // 16,777,216 f  (xz / qkv / ff1)
  float* bufB = bufA + 16777216;      //  8,388,608 f  (xc / ao)
  float* bufC = bufB + 8388608;       //  8,388,608 f  (dt)
  float* bufE = bufC + 8388608;       //  4,194,304 f  (mamba-out / attn-proj / ff2)
  float* bufF = bufE + 4194304;       //    524,288 f  (xdb)
  const int M = MTOK;

  proj_kernel<<<16384, 256, 0, stream>>>(x, proj_w, proj_b, h);

  for (int i = 0; i < 2; ++i) {
    // xz = h @ in_w^T   (8192 x 2048)
    gemm_tn<0><<<dim3(2 * DINNER / 64, M / 64), 256, 0, stream>>>(
        h, m_in_w + (size_t)i * 2 * DINNER * DMODEL, nullptr, bufA,
        M, 2 * DINNER, DMODEL, DMODEL, 2 * DINNER);
    // xc = silu(causal_conv(xm))
    conv_silu_kernel<<<32768, 256, 0, stream>>>(bufA, m_conv_w + i * DINNER * 4,
                                                m_conv_b + i * DINNER, bufB);
    // xdb = xc @ xp_w^T  (8192 x 64)
    gemm_tn<0><<<dim3(1, M / 64), 256, 0, stream>>>(
        bufB, m_xproj_w + (size_t)i * 64 * DINNER, nullptr, bufF,
        M, 64, DINNER, DINNER, 64);
    // dt = softplus(xdb[:, :32] @ dt_w^T + dt_b)  (8192 x 1024)
    gemm_tn<2><<<dim3(DINNER / 64, M / 64), 256, 0, stream>>>(
        bufF, m_dt_w + (size_t)i * DINNER * DTRANK, m_dt_b + i * DINNER, bufC,
        M, DINNER, DTRANK, 64, DINNER);
    // selective scan -> gated y written into xz[:, :1024] slots
    scan_kernel<<<32, 256, 0, stream>>>(bufC, bufF, bufB, bufA,
                                        m_Alog + (size_t)i * DINNER * DSTATE,
                                        m_D + i * DINNER);
    // mamba_out = y @ out_w^T  (8192 x 512), A has lda=2048
    gemm_tn<0><<<dim3(DMODEL / 64, M / 64), 256, 0, stream>>>(
        bufA, m_out_w + (size_t)i * DMODEL * DINNER, nullptr, bufE,
        M, DMODEL, DINNER, 2 * DINNER, DMODEL);
    // h = LN(h + mamba_out)
    resid_ln_kernel<<<8192, 128, 0, stream>>>(h, bufE, m_ln_w + i * DMODEL,
                                              m_ln_b + i * DMODEL, h);
  }

  posenc_kernel<<<16384, 256, 0, stream>>>(h);

  for (int i = 0; i < 2; ++i) {
    // qkv = h @ qkv_w^T + qkv_b  (8192 x 1536)
    gemm_tn<0><<<dim3(3 * DMODEL / 64, M / 64), 256, 0, stream>>>(
        h, t_qkv_w + (size_t)i * 3 * DMODEL * DMODEL, t_qkv_b + i * 3 * DMODEL, bufA,
        M, 3 * DMODEL, DMODEL, DMODEL, 3 * DMODEL);
    // attention -> ao (8192 x 512)
    attn_kernel<<<16384, 256, 0, stream>>>(bufA, bufB);
    // attn_proj = ao @ ow^T + ob
    gemm_tn<0><<<dim3(DMODEL / 64, M / 64), 256, 0, stream>>>(
        bufB, t_ow + (size_t)i * DMODEL * DMODEL, t_ob + i * DMODEL, bufE,
        M, DMODEL, DMODEL, DMODEL, DMODEL);
    // h = LN(h + attn_proj)
    resid_ln_kernel<<<8192, 128, 0, stream>>>(h, bufE, t_ln1w + i * DMODEL,
                                              t_ln1b + i * DMODEL, h);
    // ff1 = relu(h @ l1w^T + l1b)  (8192 x 2048)
    gemm_tn<1><<<dim3(DFF / 64, M / 64), 256, 0, stream>>>(
        h, t_l1w + (size_t)i * DFF * DMODEL, t_l1b + i * DFF, bufA,
        M, DFF, DMODEL, DMODEL, DFF);
    // ff2 = ff1 @ l2w^T + l2b  (8192 x 512)
    gemm_tn<0><<<dim3(DMODEL / 64, M / 64), 256, 0, stream>>>(
        bufA, t_l2w + (size_t)i * DMODEL * DFF, t_l2b + i * DMODEL, bufE,
        M, DMODEL, DFF, DFF, DMODEL);
    // h = LN(h + ff2)
    resid_ln_kernel<<<8192, 128, 0, stream>>>(h, bufE, t_ln2w + i * DMODEL,
                                              t_ln2b + i * DMODEL, h);
  }

  // final LN -> d_out, then mean over L -> d_out tail
  float* out_h = (float*)d_out;
  resid_ln_kernel<<<8192, 128, 0, stream>>>(h, nullptr, no_w, no_b, out_h);
  mean_kernel<<<16, 256, 0, stream>>>(out_h, out_h + 4194304);
}

// Round 2
// 3485.523 us; speedup vs baseline: 2.7624x; 2.7624x over previous
//
#include <hip/hip_runtime.h>
#include <cstddef>

// Problem constants
#define BATCH 8
#define LSEQ 1024
#define DMODEL 512
#define DINNER 1024
#define DSTATE 16
#define DTRANK 32
#define NHEAD 8
#define DHEAD 64
#define DFF 2048
#define MTOK 8192   // BATCH*LSEQ

typedef __attribute__((ext_vector_type(8))) short bfrag;   // 8 bf16 (4 VGPRs)
typedef __attribute__((ext_vector_type(4))) float f32x4;   // MFMA acc

__device__ __forceinline__ float silu_f(float x) { return x / (1.f + __expf(-x)); }

__device__ __forceinline__ unsigned short f2bf(float f) {  // RNE fp32->bf16
  unsigned u = __float_as_uint(f);
  return (unsigned short)((u + 0x7FFFu + ((u >> 16) & 1u)) >> 16);
}

// ---------------------------------------------------------------------------
// Input projection: h[b,l,d] = sum_c x[b,c,l] * pw[d,c] + pb[d]
// ---------------------------------------------------------------------------
__global__ __launch_bounds__(256) void proj_kernel(const float* __restrict__ x,
                                                   const float* __restrict__ pw,
                                                   const float* __restrict__ pb,
                                                   float* __restrict__ h) {
  int idx = blockIdx.x * 256 + threadIdx.x;        // ((b*L)+l)*512 + d
  int d = idx & 511;
  int l = (idx >> 9) & 1023;
  int b = idx >> 19;
  const float* xb = x + (size_t)b * 3 * 1024 + l;
  h[idx] = pb[d] + xb[0] * pw[d * 3] + xb[1024] * pw[d * 3 + 1] + xb[2048] * pw[d * 3 + 2];
}

// ---------------------------------------------------------------------------
// bf16 MFMA GEMM: C[m,n] = act( sum_k A[m,k]*W[n,k] + bias[n] )
// A (fp32, lda), W (fp32, ld K) converted RNE->bf16 during LDS staging.
// Tile 128x128, BK=32, 4 waves of 64x64. ACT: 0 none, 1 relu.
// ---------------------------------------------------------------------------
template <int ACT>
__global__ __launch_bounds__(256) void gemm_mfma(const float* __restrict__ A,
                                                 const float* __restrict__ W,
                                                 const float* __restrict__ bias,
                                                 float* __restrict__ C,
                                                 int K, int lda, int ldc) {
  __shared__ bfrag Abuf[512];   // 128 rows x 4 chunks (8 bf16 each), swizzled
  __shared__ bfrag Bbuf[512];
  const int bm = blockIdx.y * 128, bn = blockIdx.x * 128;
  const int tid = threadIdx.x;
  const int wid = tid >> 6, lane = tid & 63;
  const int wr = wid >> 1, wc = wid & 1;
  const int lr = lane & 15, ls = lane >> 4;
  const int sw = ls ^ ((lr >> 1) & 3);            // read-side chunk swizzle

  f32x4 acc[4][4];
#pragma unroll
  for (int i = 0; i < 4; ++i)
#pragma unroll
    for (int j = 0; j < 4; ++j) acc[i][j] = (f32x4)(0.f);

  for (int k0 = 0; k0 < K; k0 += 32) {
    if (k0) __syncthreads();
    // stage A and B tiles (fp32 -> bf16), 512 chunks each, 2 per thread
    for (int c = tid; c < 512; c += 256) {
      int r = c >> 2, s = c & 3;
      int di = (r << 2) + (s ^ ((r >> 1) & 3));
      union { bfrag v; unsigned short u[8]; } pk;
      {
        const float* ap = A + (size_t)(bm + r) * lda + k0 + s * 8;
        float4 f0 = *(const float4*)ap, f1 = *(const float4*)(ap + 4);
        pk.u[0] = f2bf(f0.x); pk.u[1] = f2bf(f0.y); pk.u[2] = f2bf(f0.z); pk.u[3] = f2bf(f0.w);
        pk.u[4] = f2bf(f1.x); pk.u[5] = f2bf(f1.y); pk.u[6] = f2bf(f1.z); pk.u[7] = f2bf(f1.w);
        Abuf[di] = pk.v;
      }
      {
        const float* bp = W + (size_t)(bn + r) * K + k0 + s * 8;
        float4 f0 = *(const float4*)bp, f1 = *(const float4*)(bp + 4);
        pk.u[0] = f2bf(f0.x); pk.u[1] = f2bf(f0.y); pk.u[2] = f2bf(f0.z); pk.u[3] = f2bf(f0.w);
        pk.u[4] = f2bf(f1.x); pk.u[5] = f2bf(f1.y); pk.u[6] = f2bf(f1.z); pk.u[7] = f2bf(f1.w);
        Bbuf[di] = pk.v;
      }
    }
    __syncthreads();

    bfrag af[4], bf[4];
#pragma unroll
    for (int mi = 0; mi < 4; ++mi) {
      int row = wr * 64 + mi * 16 + lr;
      af[mi] = Abuf[(row << 2) + sw];
    }
#pragma unroll
    for (int nj = 0; nj < 4; ++nj) {
      int col = wc * 64 + nj * 16 + lr;
      bf[nj] = Bbuf[(col << 2) + sw];
    }
#pragma unroll
    for (int mi = 0; mi < 4; ++mi)
#pragma unroll
      for (int nj = 0; nj < 4; ++nj)
        acc[mi][nj] = __builtin_amdgcn_mfma_f32_16x16x32_bf16(af[mi], bf[nj], acc[mi][nj], 0, 0, 0);
  }

  // epilogue: C/D layout col=lane&15, row=(lane>>4)*4+reg
#pragma unroll
  for (int nj = 0; nj < 4; ++nj) {
    int col = bn + wc * 64 + nj * 16 + lr;
    float bv = bias ? bias[col] : 0.f;
#pragma unroll
    for (int mi = 0; mi < 4; ++mi) {
      int row0 = bm + wr * 64 + mi * 16 + ls * 4;
#pragma unroll
      for (int r = 0; r < 4; ++r) {
        float v = acc[mi][nj][r] + bv;
        if (ACT == 1) v = fmaxf(v, 0.f);
        C[(size_t)(row0 + r) * ldc + col] = v;
      }
    }
  }
}

// ---------------------------------------------------------------------------
// Generic fp32 tiled SGEMM (kept for small shapes: xproj N=64, dt K=32)
// ACT: 0 none, 2 softplus
// ---------------------------------------------------------------------------
template <int ACT>
__global__ __launch_bounds__(256) void gemm_tn(const float* __restrict__ A,
                                               const float* __restrict__ W,
                                               const float* __restrict__ bias,
                                               float* __restrict__ C,
                                               int M, int N, int K, int lda, int ldc) {
  __shared__ float As[16][65];
  __shared__ float Ws[16][65];
  const int bm = blockIdx.y * 64, bn = blockIdx.x * 64;
  const int tid = threadIdx.x;
  const int lk = tid & 15, lr = tid >> 4;
  const int tx = tid & 15, ty = tid >> 4;
  float acc[4][4] = {};
  for (int k0 = 0; k0 < K; k0 += 16) {
#pragma unroll
    for (int i = 0; i < 4; ++i) {
      As[lk][lr + 16 * i] = A[(size_t)(bm + lr + 16 * i) * lda + k0 + lk];
      Ws[lk][lr + 16 * i] = W[(size_t)(bn + lr + 16 * i) * K + k0 + lk];
    }
    __syncthreads();
#pragma unroll
    for (int kk = 0; kk < 16; ++kk) {
      float a[4], w[4];
#pragma unroll
      for (int i = 0; i < 4; ++i) a[i] = As[kk][ty + 16 * i];
#pragma unroll
      for (int j = 0; j < 4; ++j) w[j] = Ws[kk][tx + 16 * j];
#pragma unroll
      for (int i = 0; i < 4; ++i)
#pragma unroll
        for (int j = 0; j < 4; ++j) acc[i][j] += a[i] * w[j];
    }
    __syncthreads();
  }
#pragma unroll
  for (int i = 0; i < 4; ++i) {
    int r = bm + ty + 16 * i;
#pragma unroll
    for (int j = 0; j < 4; ++j) {
      int c = bn + tx + 16 * j;
      float v = acc[i][j];
      if (bias) v += bias[c];
      if (ACT == 2) v = (v > 20.f) ? v : log1pf(__expf(v));
      C[(size_t)r * ldc + c] = v;
    }
  }
}

// ---------------------------------------------------------------------------
// Depthwise causal conv (width 4) + SiLU.  xm = xz[:, :DINNER] (row stride 2048)
// ---------------------------------------------------------------------------
__global__ __launch_bounds__(256) void conv_silu_kernel(const float* __restrict__ xz,
                                                        const float* __restrict__ cw,
                                                        const float* __restrict__ cb,
                                                        float* __restrict__ xc) {
  int idx = blockIdx.x * 256 + threadIdx.x;        // ((b*L)+t)*1024 + d
  int d = idx & 1023;
  int t = (idx >> 10) & 1023;
  int b = idx >> 20;
  float acc = cb[d];
#pragma unroll
  for (int w = 0; w < 4; ++w) {
    int tt = t - 3 + w;
    if (tt >= 0) acc += xz[(((size_t)(b * 1024 + tt)) << 11) + d] * cw[d * 4 + w];
  }
  xc[idx] = silu_f(acc);
}

// ---------------------------------------------------------------------------
// Selective scan: one thread per (b,d) channel, 16 states in registers.
// ---------------------------------------------------------------------------
__global__ __launch_bounds__(256) void scan_kernel(const float* __restrict__ dt,
                                                   const float* __restrict__ xdb,
                                                   const float* __restrict__ xc,
                                                   float* __restrict__ xz,
                                                   const float* __restrict__ Alog,
                                                   const float* __restrict__ Dp) {
  int idx = blockIdx.x * 256 + threadIdx.x;        // b*1024 + d
  int b = idx >> 10, d = idx & 1023;
  float A[16], st[16];
#pragma unroll
  for (int s = 0; s < 16; ++s) {
    A[s] = -__expf(Alog[d * 16 + s]);
    st[s] = 0.f;
  }
  float Dv = Dp[d];
  for (int t = 0; t < 1024; ++t) {
    size_t base = (((size_t)(b * 1024 + t)) << 10) + d;
    float dtv = dt[base];
    float xv = xc[base];
    size_t xrow = (size_t)(b * 1024 + t) * 64;
    float dx = dtv * xv;
    float acc = 0.f;
#pragma unroll
    for (int s = 0; s < 16; ++s) {
      st[s] = st[s] * __expf(dtv * A[s]) + dx * xdb[xrow + 32 + s];
      acc += st[s] * xdb[xrow + 48 + s];
    }
    size_t zrow = ((size_t)(b * 1024 + t)) << 11;
    float zv = xz[zrow + 1024 + d];
    xz[zrow + d] = (acc + Dv * xv) * silu_f(zv);
  }
}

// ---------------------------------------------------------------------------
// Residual + LayerNorm (in-place capable). add may be nullptr.
// ---------------------------------------------------------------------------
__global__ __launch_bounds__(128) void resid_ln_kernel(const float* __restrict__ x,
                                                       const float* __restrict__ add,
                                                       const float* __restrict__ w,
                                                       const float* __restrict__ bias,
                                                       float* __restrict__ out) {
  int row = blockIdx.x, tid = threadIdx.x;
  float4 v = ((const float4*)(x + (size_t)row * 512))[tid];
  if (add) {
    float4 a = ((const float4*)(add + (size_t)row * 512))[tid];
    v.x += a.x; v.y += a.y; v.z += a.z; v.w += a.w;
  }
  float s = v.x + v.y + v.z + v.w;
  float ss = v.x * v.x + v.y * v.y + v.z * v.z + v.w * v.w;
#pragma unroll
  for (int o = 32; o; o >>= 1) {
    s += __shfl_xor(s, o);
    ss += __shfl_xor(ss, o);
  }
  __shared__ float red[4];
  int wid = tid >> 6;
  if ((tid & 63) == 0) { red[wid] = s; red[2 + wid] = ss; }
  __syncthreads();
  s = red[0] + red[1];
  ss = red[2] + red[3];
  float mean = s * (1.f / 512.f);
  float var = ss * (1.f / 512.f) - mean * mean;
  float inv = rsqrtf(var + 1e-5f);
  float4 wv = ((const float4*)w)[tid];
  float4 bv = ((const float4*)bias)[tid];
  float4 ov;
  ov.x = (v.x - mean) * inv * wv.x + bv.x;
  ov.y = (v.y - mean) * inv * wv.y + bv.y;
  ov.z = (v.z - mean) * inv * wv.z + bv.z;
  ov.w = (v.w - mean) * inv * wv.w + bv.w;
  ((float4*)(out + (size_t)row * 512))[tid] = ov;
}

// ---------------------------------------------------------------------------
// Sinusoidal positional encoding add (in-place on h)
// ---------------------------------------------------------------------------
__global__ __launch_bounds__(256) void posenc_kernel(float* __restrict__ h) {
  int idx = blockIdx.x * 256 + threadIdx.x;
  int d = idx & 511;
  int l = (idx >> 9) & 1023;
  float freq = __expf(-(float)(d & ~1) * (9.210340371976184f / 512.f));
  float ang = (float)l * freq;
  h[idx] += (d & 1) ? cosf(ang) : sinf(ang);
}

// ---------------------------------------------------------------------------
// Flash attention: one block per (b, head, 64-q-row tile). fp32 VALU.
// LDS tiles stride-64 with XOR swizzle c4' = c4 ^ (row&7) (conflict-free).
// Thread (ty=tid>>4, tx=tid&15) owns rows {ty+16i}, cols {tx+16j}.
// ---------------------------------------------------------------------------
__global__ __launch_bounds__(256) void attn_flash(const float* __restrict__ qkv,
                                                  float* __restrict__ ao) {
  __shared__ float Qs[4096];
  __shared__ float Ks[4096];
  __shared__ float Vs[4096];
  __shared__ float Ps[4096];
  const int tid = threadIdx.x;
  const int blk = blockIdx.x;                    // ((b*8 + h)*16 + qt)
  const int qt = blk & 15, hh = (blk >> 4) & 7, b = blk >> 7;
  const int l0 = qt * 64;
  const size_t bb = (size_t)b * 1024 * 1536;
  // stage Q (scaled by 1/sqrt(64))
  for (int f = tid; f < 1024; f += 256) {
    int r = f >> 4, c4 = f & 15;
    float4 q = *(const float4*)(qkv + bb + (size_t)(l0 + r) * 1536 + hh * 64 + c4 * 4);
    float* dst = &Qs[r * 64 + ((c4 ^ (r & 7)) << 2)];
    dst[0] = q.x * 0.125f; dst[1] = q.y * 0.125f; dst[2] = q.z * 0.125f; dst[3] = q.w * 0.125f;
  }
  const int ty = tid >> 4, tx = tid & 15;
  const int tyw = ty & 7, txw = tx & 7;
  float m[4], lsum[4], acc[4][4];
#pragma unroll
  for (int i = 0; i < 4; ++i) {
    m[i] = -1e30f; lsum[i] = 0.f;
#pragma unroll
    for (int j = 0; j < 4; ++j) acc[i][j] = 0.f;
  }
  __syncthreads();

  for (int jt = 0; jt < 16; ++jt) {
    // stage K,V tiles (coalesced), swizzled
    for (int f = tid; f < 1024; f += 256) {
      int r = f >> 4, c4 = f & 15;
      size_t grow = bb + (size_t)(jt * 64 + r) * 1536 + hh * 64 + c4 * 4;
      int di = r * 64 + ((c4 ^ (r & 7)) << 2);
      *(float4*)&Ks[di] = *(const float4*)(qkv + grow + 512);
      *(float4*)&Vs[di] = *(const float4*)(qkv + grow + 1024);
    }
    __syncthreads();

    // S = Q K^T  (4x4 per thread)
    float s[4][4] = {};
#pragma unroll
    for (int d4 = 0; d4 < 16; ++d4) {
      float4 a[4], bq[4];
#pragma unroll
      for (int i = 0; i < 4; ++i)
        a[i] = *(const float4*)&Qs[(ty + 16 * i) * 64 + ((d4 ^ tyw) << 2)];
#pragma unroll
      for (int j = 0; j < 4; ++j)
        bq[j] = *(const float4*)&Ks[(tx + 16 * j) * 64 + ((d4 ^ txw) << 2)];
#pragma unroll
      for (int i = 0; i < 4; ++i)
#pragma unroll
        for (int j = 0; j < 4; ++j)
          s[i][j] += a[i].x * bq[j].x + a[i].y * bq[j].y + a[i].z * bq[j].z + a[i].w * bq[j].w;
    }

    // online softmax update (row reduce across tx via shfl_xor widths 1..8)
#pragma unroll
    for (int i = 0; i < 4; ++i) {
      float mc = fmaxf(fmaxf(s[i][0], s[i][1]), fmaxf(s[i][2], s[i][3]));
#pragma unroll
      for (int o = 8; o; o >>= 1) mc = fmaxf(mc, __shfl_xor(mc, o));
      float mn = fmaxf(m[i], mc);
      float al = __expf(m[i] - mn);
      int r = ty + 16 * i;
      float ps = 0.f;
#pragma unroll
      for (int j = 0; j < 4; ++j) {
        float p = __expf(s[i][j] - mn);
        int c = tx + 16 * j;
        Ps[r * 64 + ((((c >> 2) ^ tyw)) << 2) + (c & 3)] = p;
        ps += p;
      }
#pragma unroll
      for (int o = 8; o; o >>= 1) ps += __shfl_xor(ps, o);
      lsum[i] = lsum[i] * al + ps;
      m[i] = mn;
#pragma unroll
      for (int j = 0; j < 4; ++j) acc[i][j] *= al;
    }
    __syncthreads();

    // O += P V  (4x4 per thread)
#pragma unroll
    for (int k4 = 0; k4 < 16; ++k4) {
      float4 pa[4];
#pragma unroll
      for (int i = 0; i < 4; ++i)
        pa[i] = *(const float4*)&Ps[(ty + 16 * i) * 64 + ((k4 ^ tyw) << 2)];
#pragma unroll
      for (int dk = 0; dk < 4; ++dk) {
        int kk = k4 * 4 + dk;
        int ks = kk & 7;
        float vv[4];
#pragma unroll
        for (int j = 0; j < 4; ++j) {
          int c = tx + 16 * j;
          vv[j] = Vs[kk * 64 + (((c >> 2) ^ ks) << 2) + (c & 3)];
        }
#pragma unroll
        for (int i = 0; i < 4; ++i) {
          float pav = ((const float*)&pa[i])[dk];
#pragma unroll
          for (int j = 0; j < 4; ++j) acc[i][j] += pav * vv[j];
        }
      }
    }
    __syncthreads();
  }

  // epilogue
#pragma unroll
  for (int i = 0; i < 4; ++i) {
    float inv = 1.f / lsum[i];
    size_t row = bb / 3 + (size_t)(l0 + ty + 16 * i) * 512;  // b*1024*512 base
#pragma unroll
    for (int j = 0; j < 4; ++j)
      ao[row + hh * 64 + tx + 16 * j] = acc[i][j] * inv;
  }
}

// ---------------------------------------------------------------------------
// Mean over L: out2[b,d] = mean_l hout[b,l,d]
// ---------------------------------------------------------------------------
__global__ __launch_bounds__(256) void mean_kernel(const float* __restrict__ hout,
                                                   float* __restrict__ out2) {
  int idx = blockIdx.x * 256 + threadIdx.x;
  int b = idx >> 9, d = idx & 511;
  float s = 0.f;
  for (int l = 0; l < 1024; ++l) s += hout[(((size_t)(b * 1024 + l)) << 9) + d];
  out2[idx] = s * (1.f / 1024.f);
}

// ---------------------------------------------------------------------------
extern "C" void kernel_launch(void* const* d_in, const int* in_sizes, int n_in,
                              void* d_out, int out_size, void* d_ws, size_t ws_size,
                              hipStream_t stream) {
  const float* x        = (const float*)d_in[0];
  const float* proj_w   = (const float*)d_in[1];
  const float* proj_b   = (const float*)d_in[2];
  const float* m_in_w   = (const float*)d_in[3];
  const float* m_conv_w = (const float*)d_in[4];
  const float* m_conv_b = (const float*)d_in[5];
  const float* m_xproj_w= (const float*)d_in[6];
  const float* m_dt_w   = (const float*)d_in[7];
  const float* m_dt_b   = (const float*)d_in[8];
  const float* m_Alog   = (const float*)d_in[9];
  const float* m_D      = (const float*)d_in[10];
  const float* m_out_w  = (const float*)d_in[11];
  const float* m_ln_w   = (const float*)d_in[12];
  const float* m_ln_b   = (const float*)d_in[13];
  const float* t_qkv_w  = (const float*)d_in[14];
  const float* t_qkv_b  = (const float*)d_in[15];
  const float* t_ow     = (const float*)d_in[16];
  const float* t_ob     = (const float*)d_in[17];
  const float* t_l1w    = (const float*)d_in[18];
  const float* t_l1b    = (const float*)d_in[19];
  const float* t_l2w    = (const float*)d_in[20];
  const float* t_l2b    = (const float*)d_in[21];
  const float* t_ln1w   = (const float*)d_in[22];
  const float* t_ln1b   = (const float*)d_in[23];
  const float* t_ln2w   = (const float*)d_in[24];
  const float* t_ln2b   = (const float*)d_in[25];
  const float* no_w     = (const float*)d_in[26];
  const float* no_b     = (const float*)d_in[27];

  float* ws   = (float*)d_ws;
  float* h    = ws;                   //  4,194,304 f  (B,L,512)
  float* bufA = h + 4194304;          // 16,777,216 f  (xz / qkv / ff1)
  float* bufB = bufA + 16777216;      //  8,388,608 f  (xc / ao)
  float* bufC = bufB + 8388608;       //  8,388,608 f  (dt)
  float* bufE = bufC + 8388608;       //  4,194,304 f  (mamba-out / attn-proj / ff2)
  float* bufF = bufE + 4194304;       //    524,288 f  (xdb)
  const int M = MTOK;

  proj_kernel<<<16384, 256, 0, stream>>>(x, proj_w, proj_b, h);

  for (int i = 0; i < 2; ++i) {
    // xz = h @ in_w^T   (8192 x 2048, K=512)
    gemm_mfma<0><<<dim3(2 * DINNER / 128, M / 128), 256, 0, stream>>>(
        h, m_in_w + (size_t)i * 2 * DINNER * DMODEL, nullptr, bufA,
        DMODEL, DMODEL, 2 * DINNER);
    // xc = silu(causal_conv(xm))
    conv_silu_kernel<<<32768, 256, 0, stream>>>(bufA, m_conv_w + i * DINNER * 4,
                                                m_conv_b + i * DINNER, bufB);
    // xdb = xc @ xp_w^T  (8192 x 64, K=1024) — small N, fp32
    gemm_tn<0><<<dim3(1, M / 64), 256, 0, stream>>>(
        bufB, m_xproj_w + (size_t)i * 64 * DINNER, nullptr, bufF,
        M, 64, DINNER, DINNER, 64);
    // dt = softplus(xdb[:, :32] @ dt_w^T + dt_b)  (8192 x 1024, K=32) — fp32
    gemm_tn<2><<<dim3(DINNER / 64, M / 64), 256, 0, stream>>>(
        bufF, m_dt_w + (size_t)i * DINNER * DTRANK, m_dt_b + i * DINNER, bufC,
        M, DINNER, DTRANK, 64, DINNER);
    // selective scan -> gated y written into xz[:, :1024] slots
    scan_kernel<<<32, 256, 0, stream>>>(bufC, bufF, bufB, bufA,
                                        m_Alog + (size_t)i * DINNER * DSTATE,
                                        m_D + i * DINNER);
    // mamba_out = y @ out_w^T  (8192 x 512, K=1024, lda=2048)
    gemm_mfma<0><<<dim3(DMODEL / 128, M / 128), 256, 0, stream>>>(
        bufA, m_out_w + (size_t)i * DMODEL * DINNER, nullptr, bufE,
        DINNER, 2 * DINNER, DMODEL);
    // h = LN(h + mamba_out)
    resid_ln_kernel<<<8192, 128, 0, stream>>>(h, bufE, m_ln_w + i * DMODEL,
                                              m_ln_b + i * DMODEL, h);
  }

  posenc_kernel<<<16384, 256, 0, stream>>>(h);

  for (int i = 0; i < 2; ++i) {
    // qkv = h @ qkv_w^T + qkv_b  (8192 x 1536, K=512)
    gemm_mfma<0><<<dim3(3 * DMODEL / 128, M / 128), 256, 0, stream>>>(
        h, t_qkv_w + (size_t)i * 3 * DMODEL * DMODEL, t_qkv_b + i * 3 * DMODEL, bufA,
        DMODEL, DMODEL, 3 * DMODEL);
    // flash attention -> ao (8192 x 512)
    attn_flash<<<1024, 256, 0, stream>>>(bufA, bufB);
    // attn_proj = ao @ ow^T + ob  (8192 x 512, K=512)
    gemm_mfma<0><<<dim3(DMODEL / 128, M / 128), 256, 0, stream>>>(
        bufB, t_ow + (size_t)i * DMODEL * DMODEL, t_ob + i * DMODEL, bufE,
        DMODEL, DMODEL, DMODEL);
    // h = LN(h + attn_proj)
    resid_ln_kernel<<<8192, 128, 0, stream>>>(h, bufE, t_ln1w + i * DMODEL,
                                              t_ln1b + i * DMODEL, h);
    // ff1 = relu(h @ l1w^T + l1b)  (8192 x 2048, K=512)
    gemm_mfma<1><<<dim3(DFF / 128, M / 128), 256, 0, stream>>>(
        h, t_l1w + (size_t)i * DFF * DMODEL, t_l1b + i * DFF, bufA,
        DMODEL, DMODEL, DFF);
    // ff2 = ff1 @ l2w^T + l2b  (8192 x 512, K=2048)
    gemm_mfma<0><<<dim3(DMODEL / 128, M / 128), 256, 0, stream>>>(
        bufA, t_l2w + (size_t)i * DMODEL * DFF, t_l2b + i * DMODEL, bufE,
        DFF, DFF, DMODEL);
    // h = LN(h + ff2)
    resid_ln_kernel<<<8192, 128, 0, stream>>>(h, bufE, t_ln2w + i * DMODEL,
                                              t_ln2b + i * DMODEL, h);
  }

  // final LN -> d_out, then mean over L -> d_out tail
  float* out_h = (float*)d_out;
  resid_ln_kernel<<<8192, 128, 0, stream>>>(h, nullptr, no_w, no_b, out_h);
  mean_kernel<<<16, 256, 0, stream>>>(out_h, out_h + 4194304);
}

// Round 3
// 1996.833 us; speedup vs baseline: 4.8218x; 1.7455x over previous
//
#include <hip/hip_runtime.h>
#include <cstddef>

// Problem constants
#define BATCH 8
#define LSEQ 1024
#define DMODEL 512
#define DINNER 1024
#define DSTATE 16
#define DTRANK 32
#define NHEAD 8
#define DHEAD 64
#define DFF 2048
#define MTOK 8192   // BATCH*LSEQ
#define NCHUNK 16
#define CLEN 64     // LSEQ / NCHUNK

typedef __attribute__((ext_vector_type(8))) short bfrag;   // 8 bf16 (4 VGPRs)
typedef __attribute__((ext_vector_type(4))) float f32x4;   // MFMA acc

__device__ __forceinline__ float silu_f(float x) { return x / (1.f + __expf(-x)); }

__device__ __forceinline__ unsigned short f2bf(float f) {  // RNE fp32->bf16
  unsigned u = __float_as_uint(f);
  return (unsigned short)((u + 0x7FFFu + ((u >> 16) & 1u)) >> 16);
}

// ---------------------------------------------------------------------------
// Input projection: h[b,l,d] = sum_c x[b,c,l] * pw[d,c] + pb[d]
// ---------------------------------------------------------------------------
__global__ __launch_bounds__(256) void proj_kernel(const float* __restrict__ x,
                                                   const float* __restrict__ pw,
                                                   const float* __restrict__ pb,
                                                   float* __restrict__ h) {
  int idx = blockIdx.x * 256 + threadIdx.x;        // ((b*L)+l)*512 + d
  int d = idx & 511;
  int l = (idx >> 9) & 1023;
  int b = idx >> 19;
  const float* xb = x + (size_t)b * 3 * 1024 + l;
  h[idx] = pb[d] + xb[0] * pw[d * 3] + xb[1024] * pw[d * 3 + 1] + xb[2048] * pw[d * 3 + 2];
}

// ---------------------------------------------------------------------------
// bf16 MFMA GEMM: C[m,n] = act( sum_k A[m,k]*W[n,k] + bias[n] )
// A (fp32, lda), W (fp32, ld K) converted RNE->bf16 during LDS staging.
// Tile 128x128, BK=32, 4 waves of 64x64. ACT: 0 none, 1 relu.
// ---------------------------------------------------------------------------
template <int ACT>
__global__ __launch_bounds__(256) void gemm_mfma(const float* __restrict__ A,
                                                 const float* __restrict__ W,
                                                 const float* __restrict__ bias,
                                                 float* __restrict__ C,
                                                 int K, int lda, int ldc) {
  __shared__ bfrag Abuf[512];   // 128 rows x 4 chunks (8 bf16 each), swizzled
  __shared__ bfrag Bbuf[512];
  const int bm = blockIdx.y * 128, bn = blockIdx.x * 128;
  const int tid = threadIdx.x;
  const int wid = tid >> 6, lane = tid & 63;
  const int wr = wid >> 1, wc = wid & 1;
  const int lr = lane & 15, ls = lane >> 4;
  const int sw = ls ^ ((lr >> 1) & 3);            // read-side chunk swizzle

  f32x4 acc[4][4];
#pragma unroll
  for (int i = 0; i < 4; ++i)
#pragma unroll
    for (int j = 0; j < 4; ++j) acc[i][j] = (f32x4)(0.f);

  for (int k0 = 0; k0 < K; k0 += 32) {
    if (k0) __syncthreads();
    // stage A and B tiles (fp32 -> bf16), 512 chunks each, 2 per thread
    for (int c = tid; c < 512; c += 256) {
      int r = c >> 2, s = c & 3;
      int di = (r << 2) + (s ^ ((r >> 1) & 3));
      union { bfrag v; unsigned short u[8]; } pk;
      {
        const float* ap = A + (size_t)(bm + r) * lda + k0 + s * 8;
        float4 f0 = *(const float4*)ap, f1 = *(const float4*)(ap + 4);
        pk.u[0] = f2bf(f0.x); pk.u[1] = f2bf(f0.y); pk.u[2] = f2bf(f0.z); pk.u[3] = f2bf(f0.w);
        pk.u[4] = f2bf(f1.x); pk.u[5] = f2bf(f1.y); pk.u[6] = f2bf(f1.z); pk.u[7] = f2bf(f1.w);
        Abuf[di] = pk.v;
      }
      {
        const float* bp = W + (size_t)(bn + r) * K + k0 + s * 8;
        float4 f0 = *(const float4*)bp, f1 = *(const float4*)(bp + 4);
        pk.u[0] = f2bf(f0.x); pk.u[1] = f2bf(f0.y); pk.u[2] = f2bf(f0.z); pk.u[3] = f2bf(f0.w);
        pk.u[4] = f2bf(f1.x); pk.u[5] = f2bf(f1.y); pk.u[6] = f2bf(f1.z); pk.u[7] = f2bf(f1.w);
        Bbuf[di] = pk.v;
      }
    }
    __syncthreads();

    bfrag af[4], bf[4];
#pragma unroll
    for (int mi = 0; mi < 4; ++mi) {
      int row = wr * 64 + mi * 16 + lr;
      af[mi] = Abuf[(row << 2) + sw];
    }
#pragma unroll
    for (int nj = 0; nj < 4; ++nj) {
      int col = wc * 64 + nj * 16 + lr;
      bf[nj] = Bbuf[(col << 2) + sw];
    }
#pragma unroll
    for (int mi = 0; mi < 4; ++mi)
#pragma unroll
      for (int nj = 0; nj < 4; ++nj)
        acc[mi][nj] = __builtin_amdgcn_mfma_f32_16x16x32_bf16(af[mi], bf[nj], acc[mi][nj], 0, 0, 0);
  }

  // epilogue: C/D layout col=lane&15, row=(lane>>4)*4+reg
#pragma unroll
  for (int nj = 0; nj < 4; ++nj) {
    int col = bn + wc * 64 + nj * 16 + lr;
    float bv = bias ? bias[col] : 0.f;
#pragma unroll
    for (int mi = 0; mi < 4; ++mi) {
      int row0 = bm + wr * 64 + mi * 16 + ls * 4;
#pragma unroll
      for (int r = 0; r < 4; ++r) {
        float v = acc[mi][nj][r] + bv;
        if (ACT == 1) v = fmaxf(v, 0.f);
        C[(size_t)(row0 + r) * ldc + col] = v;
      }
    }
  }
}

// ---------------------------------------------------------------------------
// Generic fp32 tiled SGEMM (kept for small shapes: xproj N=64, dt K=32)
// ACT: 0 none, 2 softplus
// ---------------------------------------------------------------------------
template <int ACT>
__global__ __launch_bounds__(256) void gemm_tn(const float* __restrict__ A,
                                               const float* __restrict__ W,
                                               const float* __restrict__ bias,
                                               float* __restrict__ C,
                                               int M, int N, int K, int lda, int ldc) {
  __shared__ float As[16][65];
  __shared__ float Ws[16][65];
  const int bm = blockIdx.y * 64, bn = blockIdx.x * 64;
  const int tid = threadIdx.x;
  const int lk = tid & 15, lr = tid >> 4;
  const int tx = tid & 15, ty = tid >> 4;
  float acc[4][4] = {};
  for (int k0 = 0; k0 < K; k0 += 16) {
#pragma unroll
    for (int i = 0; i < 4; ++i) {
      As[lk][lr + 16 * i] = A[(size_t)(bm + lr + 16 * i) * lda + k0 + lk];
      Ws[lk][lr + 16 * i] = W[(size_t)(bn + lr + 16 * i) * K + k0 + lk];
    }
    __syncthreads();
#pragma unroll
    for (int kk = 0; kk < 16; ++kk) {
      float a[4], w[4];
#pragma unroll
      for (int i = 0; i < 4; ++i) a[i] = As[kk][ty + 16 * i];
#pragma unroll
      for (int j = 0; j < 4; ++j) w[j] = Ws[kk][tx + 16 * j];
#pragma unroll
      for (int i = 0; i < 4; ++i)
#pragma unroll
        for (int j = 0; j < 4; ++j) acc[i][j] += a[i] * w[j];
    }
    __syncthreads();
  }
#pragma unroll
  for (int i = 0; i < 4; ++i) {
    int r = bm + ty + 16 * i;
#pragma unroll
    for (int j = 0; j < 4; ++j) {
      int c = bn + tx + 16 * j;
      float v = acc[i][j];
      if (bias) v += bias[c];
      if (ACT == 2) v = (v > 20.f) ? v : log1pf(__expf(v));
      C[(size_t)r * ldc + c] = v;
    }
  }
}

// ---------------------------------------------------------------------------
// Depthwise causal conv (width 4) + SiLU.  xm = xz[:, :DINNER] (row stride 2048)
// ---------------------------------------------------------------------------
__global__ __launch_bounds__(256) void conv_silu_kernel(const float* __restrict__ xz,
                                                        const float* __restrict__ cw,
                                                        const float* __restrict__ cb,
                                                        float* __restrict__ xc) {
  int idx = blockIdx.x * 256 + threadIdx.x;        // ((b*L)+t)*1024 + d
  int d = idx & 1023;
  int t = (idx >> 10) & 1023;
  int b = idx >> 20;
  float acc = cb[d];
#pragma unroll
  for (int w = 0; w < 4; ++w) {
    int tt = t - 3 + w;
    if (tt >= 0) acc += xz[(((size_t)(b * 1024 + tt)) << 11) + d] * cw[d * 4 + w];
  }
  xc[idx] = silu_f(acc);
}

// ---------------------------------------------------------------------------
// Chunked selective scan, pass 1: per (b,d,chunk) scan 64 steps with init=0.
// Tracks local state st[16] and exact decay product P[16]; stores both.
// scrP layout: [((b*16+c)*16+s)*1024 + d]; scrL same in second half.
// ---------------------------------------------------------------------------
__global__ __launch_bounds__(256) void scan_pass1(const float* __restrict__ dt,
                                                  const float* __restrict__ xdb,
                                                  const float* __restrict__ xc,
                                                  const float* __restrict__ Alog,
                                                  float* __restrict__ scrP,
                                                  float* __restrict__ scrL) {
  int idx = blockIdx.x * 256 + threadIdx.x;        // ((b*16 + c)*1024 + d)
  int d = idx & 1023;
  int c = (idx >> 10) & 15;
  int b = idx >> 14;
  float A[16], st[16], P[16];
#pragma unroll
  for (int s = 0; s < 16; ++s) {
    A[s] = -__expf(Alog[d * 16 + s]);
    st[s] = 0.f;
    P[s] = 1.f;
  }
  int t0 = c * CLEN;
  for (int t = t0; t < t0 + CLEN; ++t) {
    size_t base = (((size_t)(b * 1024 + t)) << 10) + d;
    float dtv = dt[base];
    float xv = xc[base];
    size_t xrow = (size_t)(b * 1024 + t) * 64;
    float dx = dtv * xv;
#pragma unroll
    for (int s = 0; s < 16; ++s) {
      float e = __expf(dtv * A[s]);
      st[s] = st[s] * e + dx * xdb[xrow + 32 + s];
      P[s] *= e;
    }
  }
  size_t pbase = (((size_t)((b * 16 + c) * 16)) << 10) + d;
#pragma unroll
  for (int s = 0; s < 16; ++s) {
    scrP[pbase + ((size_t)s << 10)] = P[s];
    scrL[pbase + ((size_t)s << 10)] = st[s];
  }
}

// ---------------------------------------------------------------------------
// Pass 2: combine chunks serially per (b,d,s). Overwrites scrL[chunk] with the
// INCOMING init state for that chunk.
// ---------------------------------------------------------------------------
__global__ __launch_bounds__(256) void scan_pass2(const float* __restrict__ scrP,
                                                  float* __restrict__ scrL) {
  int idx = blockIdx.x * 256 + threadIdx.x;        // ((b*16 + s)*1024 + d)
  int d = idx & 1023;
  int s = (idx >> 10) & 15;
  int b = idx >> 14;
  float cur = 0.f;
  for (int c = 0; c < 16; ++c) {
    size_t o = (((size_t)(((b * 16 + c) * 16) + s)) << 10) + d;
    float P = scrP[o];
    float loc = scrL[o];
    scrL[o] = cur;
    cur = cur * P + loc;
  }
}

// ---------------------------------------------------------------------------
// Pass 3: rescan each chunk with correct init, produce gated y into xz[:, :1024].
// ---------------------------------------------------------------------------
__global__ __launch_bounds__(256) void scan_pass3(const float* __restrict__ dt,
                                                  const float* __restrict__ xdb,
                                                  const float* __restrict__ xc,
                                                  float* __restrict__ xz,
                                                  const float* __restrict__ Alog,
                                                  const float* __restrict__ Dp,
                                                  const float* __restrict__ scrL) {
  int idx = blockIdx.x * 256 + threadIdx.x;        // ((b*16 + c)*1024 + d)
  int d = idx & 1023;
  int c = (idx >> 10) & 15;
  int b = idx >> 14;
  float A[16], st[16];
  size_t pbase = (((size_t)((b * 16 + c) * 16)) << 10) + d;
#pragma unroll
  for (int s = 0; s < 16; ++s) {
    A[s] = -__expf(Alog[d * 16 + s]);
    st[s] = scrL[pbase + ((size_t)s << 10)];
  }
  float Dv = Dp[d];
  int t0 = c * CLEN;
  for (int t = t0; t < t0 + CLEN; ++t) {
    size_t base = (((size_t)(b * 1024 + t)) << 10) + d;
    float dtv = dt[base];
    float xv = xc[base];
    size_t xrow = (size_t)(b * 1024 + t) * 64;
    float dx = dtv * xv;
    float acc = 0.f;
#pragma unroll
    for (int s = 0; s < 16; ++s) {
      float e = __expf(dtv * A[s]);
      st[s] = st[s] * e + dx * xdb[xrow + 32 + s];
      acc += st[s] * xdb[xrow + 48 + s];
    }
    size_t zrow = ((size_t)(b * 1024 + t)) << 11;
    float zv = xz[zrow + 1024 + d];
    xz[zrow + d] = (acc + Dv * xv) * silu_f(zv);
  }
}

// ---------------------------------------------------------------------------
// Residual + LayerNorm (in-place capable). add may be nullptr.
// ---------------------------------------------------------------------------
__global__ __launch_bounds__(128) void resid_ln_kernel(const float* __restrict__ x,
                                                       const float* __restrict__ add,
                                                       const float* __restrict__ w,
                                                       const float* __restrict__ bias,
                                                       float* __restrict__ out) {
  int row = blockIdx.x, tid = threadIdx.x;
  float4 v = ((const float4*)(x + (size_t)row * 512))[tid];
  if (add) {
    float4 a = ((const float4*)(add + (size_t)row * 512))[tid];
    v.x += a.x; v.y += a.y; v.z += a.z; v.w += a.w;
  }
  float s = v.x + v.y + v.z + v.w;
  float ss = v.x * v.x + v.y * v.y + v.z * v.z + v.w * v.w;
#pragma unroll
  for (int o = 32; o; o >>= 1) {
    s += __shfl_xor(s, o);
    ss += __shfl_xor(ss, o);
  }
  __shared__ float red[4];
  int wid = tid >> 6;
  if ((tid & 63) == 0) { red[wid] = s; red[2 + wid] = ss; }
  __syncthreads();
  s = red[0] + red[1];
  ss = red[2] + red[3];
  float mean = s * (1.f / 512.f);
  float var = ss * (1.f / 512.f) - mean * mean;
  float inv = rsqrtf(var + 1e-5f);
  float4 wv = ((const float4*)w)[tid];
  float4 bv = ((const float4*)bias)[tid];
  float4 ov;
  ov.x = (v.x - mean) * inv * wv.x + bv.x;
  ov.y = (v.y - mean) * inv * wv.y + bv.y;
  ov.z = (v.z - mean) * inv * wv.z + bv.z;
  ov.w = (v.w - mean) * inv * wv.w + bv.w;
  ((float4*)(out + (size_t)row * 512))[tid] = ov;
}

// ---------------------------------------------------------------------------
// Sinusoidal positional encoding add (in-place on h)
// ---------------------------------------------------------------------------
__global__ __launch_bounds__(256) void posenc_kernel(float* __restrict__ h) {
  int idx = blockIdx.x * 256 + threadIdx.x;
  int d = idx & 511;
  int l = (idx >> 9) & 1023;
  float freq = __expf(-(float)(d & ~1) * (9.210340371976184f / 512.f));
  float ang = (float)l * freq;
  h[idx] += (d & 1) ? cosf(ang) : sinf(ang);
}

// ---------------------------------------------------------------------------
// Flash attention: one block per (b, head, 64-q-row tile). fp32 VALU.
// ---------------------------------------------------------------------------
__global__ __launch_bounds__(256) void attn_flash(const float* __restrict__ qkv,
                                                  float* __restrict__ ao) {
  __shared__ float Qs[4096];
  __shared__ float Ks[4096];
  __shared__ float Vs[4096];
  __shared__ float Ps[4096];
  const int tid = threadIdx.x;
  const int blk = blockIdx.x;                    // ((b*8 + h)*16 + qt)
  const int qt = blk & 15, hh = (blk >> 4) & 7, b = blk >> 7;
  const int l0 = qt * 64;
  const size_t bb = (size_t)b * 1024 * 1536;
  for (int f = tid; f < 1024; f += 256) {
    int r = f >> 4, c4 = f & 15;
    float4 q = *(const float4*)(qkv + bb + (size_t)(l0 + r) * 1536 + hh * 64 + c4 * 4);
    float* dst = &Qs[r * 64 + ((c4 ^ (r & 7)) << 2)];
    dst[0] = q.x * 0.125f; dst[1] = q.y * 0.125f; dst[2] = q.z * 0.125f; dst[3] = q.w * 0.125f;
  }
  const int ty = tid >> 4, tx = tid & 15;
  const int tyw = ty & 7, txw = tx & 7;
  float m[4], lsum[4], acc[4][4];
#pragma unroll
  for (int i = 0; i < 4; ++i) {
    m[i] = -1e30f; lsum[i] = 0.f;
#pragma unroll
    for (int j = 0; j < 4; ++j) acc[i][j] = 0.f;
  }
  __syncthreads();

  for (int jt = 0; jt < 16; ++jt) {
    for (int f = tid; f < 1024; f += 256) {
      int r = f >> 4, c4 = f & 15;
      size_t grow = bb + (size_t)(jt * 64 + r) * 1536 + hh * 64 + c4 * 4;
      int di = r * 64 + ((c4 ^ (r & 7)) << 2);
      *(float4*)&Ks[di] = *(const float4*)(qkv + grow + 512);
      *(float4*)&Vs[di] = *(const float4*)(qkv + grow + 1024);
    }
    __syncthreads();

    float s[4][4] = {};
#pragma unroll
    for (int d4 = 0; d4 < 16; ++d4) {
      float4 a[4], bq[4];
#pragma unroll
      for (int i = 0; i < 4; ++i)
        a[i] = *(const float4*)&Qs[(ty + 16 * i) * 64 + ((d4 ^ tyw) << 2)];
#pragma unroll
      for (int j = 0; j < 4; ++j)
        bq[j] = *(const float4*)&Ks[(tx + 16 * j) * 64 + ((d4 ^ txw) << 2)];
#pragma unroll
      for (int i = 0; i < 4; ++i)
#pragma unroll
        for (int j = 0; j < 4; ++j)
          s[i][j] += a[i].x * bq[j].x + a[i].y * bq[j].y + a[i].z * bq[j].z + a[i].w * bq[j].w;
    }

#pragma unroll
    for (int i = 0; i < 4; ++i) {
      float mc = fmaxf(fmaxf(s[i][0], s[i][1]), fmaxf(s[i][2], s[i][3]));
#pragma unroll
      for (int o = 8; o; o >>= 1) mc = fmaxf(mc, __shfl_xor(mc, o));
      float mn = fmaxf(m[i], mc);
      float al = __expf(m[i] - mn);
      int r = ty + 16 * i;
      float ps = 0.f;
#pragma unroll
      for (int j = 0; j < 4; ++j) {
        float p = __expf(s[i][j] - mn);
        int c = tx + 16 * j;
        Ps[r * 64 + ((((c >> 2) ^ tyw)) << 2) + (c & 3)] = p;
        ps += p;
      }
#pragma unroll
      for (int o = 8; o; o >>= 1) ps += __shfl_xor(ps, o);
      lsum[i] = lsum[i] * al + ps;
      m[i] = mn;
#pragma unroll
      for (int j = 0; j < 4; ++j) acc[i][j] *= al;
    }
    __syncthreads();

#pragma unroll
    for (int k4 = 0; k4 < 16; ++k4) {
      float4 pa[4];
#pragma unroll
      for (int i = 0; i < 4; ++i)
        pa[i] = *(const float4*)&Ps[(ty + 16 * i) * 64 + ((k4 ^ tyw) << 2)];
#pragma unroll
      for (int dk = 0; dk < 4; ++dk) {
        int kk = k4 * 4 + dk;
        int ks = kk & 7;
        float vv[4];
#pragma unroll
        for (int j = 0; j < 4; ++j) {
          int c = tx + 16 * j;
          vv[j] = Vs[kk * 64 + (((c >> 2) ^ ks) << 2) + (c & 3)];
        }
#pragma unroll
        for (int i = 0; i < 4; ++i) {
          float pav = ((const float*)&pa[i])[dk];
#pragma unroll
          for (int j = 0; j < 4; ++j) acc[i][j] += pav * vv[j];
        }
      }
    }
    __syncthreads();
  }

#pragma unroll
  for (int i = 0; i < 4; ++i) {
    float inv = 1.f / lsum[i];
    size_t row = bb / 3 + (size_t)(l0 + ty + 16 * i) * 512;
#pragma unroll
    for (int j = 0; j < 4; ++j)
      ao[row + hh * 64 + tx + 16 * j] = acc[i][j] * inv;
  }
}

// ---------------------------------------------------------------------------
// Mean over L: out2[b,d] = mean_l hout[b,l,d]
// ---------------------------------------------------------------------------
__global__ __launch_bounds__(256) void mean_kernel(const float* __restrict__ hout,
                                                   float* __restrict__ out2) {
  int idx = blockIdx.x * 256 + threadIdx.x;
  int b = idx >> 9, d = idx & 511;
  float s = 0.f;
  for (int l = 0; l < 1024; ++l) s += hout[(((size_t)(b * 1024 + l)) << 9) + d];
  out2[idx] = s * (1.f / 1024.f);
}

// ---------------------------------------------------------------------------
extern "C" void kernel_launch(void* const* d_in, const int* in_sizes, int n_in,
                              void* d_out, int out_size, void* d_ws, size_t ws_size,
                              hipStream_t stream) {
  const float* x        = (const float*)d_in[0];
  const float* proj_w   = (const float*)d_in[1];
  const float* proj_b   = (const float*)d_in[2];
  const float* m_in_w   = (const float*)d_in[3];
  const float* m_conv_w = (const float*)d_in[4];
  const float* m_conv_b = (const float*)d_in[5];
  const float* m_xproj_w= (const float*)d_in[6];
  const float* m_dt_w   = (const float*)d_in[7];
  const float* m_dt_b   = (const float*)d_in[8];
  const float* m_Alog   = (const float*)d_in[9];
  const float* m_D      = (const float*)d_in[10];
  const float* m_out_w  = (const float*)d_in[11];
  const float* m_ln_w   = (const float*)d_in[12];
  const float* m_ln_b   = (const float*)d_in[13];
  const float* t_qkv_w  = (const float*)d_in[14];
  const float* t_qkv_b  = (const float*)d_in[15];
  const float* t_ow     = (const float*)d_in[16];
  const float* t_ob     = (const float*)d_in[17];
  const float* t_l1w    = (const float*)d_in[18];
  const float* t_l1b    = (const float*)d_in[19];
  const float* t_l2w    = (const float*)d_in[20];
  const float* t_l2b    = (const float*)d_in[21];
  const float* t_ln1w   = (const float*)d_in[22];
  const float* t_ln1b   = (const float*)d_in[23];
  const float* t_ln2w   = (const float*)d_in[24];
  const float* t_ln2b   = (const float*)d_in[25];
  const float* no_w     = (const float*)d_in[26];
  const float* no_b     = (const float*)d_in[27];

  float* ws   = (float*)d_ws;
  float* h    = ws;                   //  4,194,304 f  (B,L,512)
  float* bufA = h + 4194304;          // 16,777,216 f  (xz / qkv / ff1)
  float* bufB = bufA + 16777216;      //  8,388,608 f  (xc / ao)
  float* bufC = bufB + 8388608;       //  8,388,608 f  (dt)
  float* bufE = bufC + 8388608;       //  4,194,304 f  (scan scratch / mamba-out / attn-proj / ff2)
  float* bufF = bufE + 4194304;       //    524,288 f  (xdb)
  float* scrP = bufE;                 //  2,097,152 f  (chunk decay products)
  float* scrL = bufE + 2097152;       //  2,097,152 f  (chunk local-end -> init states)
  const int M = MTOK;

  proj_kernel<<<16384, 256, 0, stream>>>(x, proj_w, proj_b, h);

  for (int i = 0; i < 2; ++i) {
    // xz = h @ in_w^T   (8192 x 2048, K=512)
    gemm_mfma<0><<<dim3(2 * DINNER / 128, M / 128), 256, 0, stream>>>(
        h, m_in_w + (size_t)i * 2 * DINNER * DMODEL, nullptr, bufA,
        DMODEL, DMODEL, 2 * DINNER);
    // xc = silu(causal_conv(xm))
    conv_silu_kernel<<<32768, 256, 0, stream>>>(bufA, m_conv_w + i * DINNER * 4,
                                                m_conv_b + i * DINNER, bufB);
    // xdb = xc @ xp_w^T  (8192 x 64, K=1024) — small N, fp32
    gemm_tn<0><<<dim3(1, M / 64), 256, 0, stream>>>(
        bufB, m_xproj_w + (size_t)i * 64 * DINNER, nullptr, bufF,
        M, 64, DINNER, DINNER, 64);
    // dt = softplus(xdb[:, :32] @ dt_w^T + dt_b)  (8192 x 1024, K=32) — fp32
    gemm_tn<2><<<dim3(DINNER / 64, M / 64), 256, 0, stream>>>(
        bufF, m_dt_w + (size_t)i * DINNER * DTRANK, m_dt_b + i * DINNER, bufC,
        M, DINNER, DTRANK, 64, DINNER);
    // chunked selective scan -> gated y written into xz[:, :1024] slots
    scan_pass1<<<512, 256, 0, stream>>>(bufC, bufF, bufB,
                                        m_Alog + (size_t)i * DINNER * DSTATE, scrP, scrL);
    scan_pass2<<<512, 256, 0, stream>>>(scrP, scrL);
    scan_pass3<<<512, 256, 0, stream>>>(bufC, bufF, bufB, bufA,
                                        m_Alog + (size_t)i * DINNER * DSTATE,
                                        m_D + i * DINNER, scrL);
    // mamba_out = y @ out_w^T  (8192 x 512, K=1024, lda=2048)
    gemm_mfma<0><<<dim3(DMODEL / 128, M / 128), 256, 0, stream>>>(
        bufA, m_out_w + (size_t)i * DMODEL * DINNER, nullptr, bufE,
        DINNER, 2 * DINNER, DMODEL);
    // h = LN(h + mamba_out)
    resid_ln_kernel<<<8192, 128, 0, stream>>>(h, bufE, m_ln_w + i * DMODEL,
                                              m_ln_b + i * DMODEL, h);
  }

  posenc_kernel<<<16384, 256, 0, stream>>>(h);

  for (int i = 0; i < 2; ++i) {
    // qkv = h @ qkv_w^T + qkv_b  (8192 x 1536, K=512)
    gemm_mfma<0><<<dim3(3 * DMODEL / 128, M / 128), 256, 0, stream>>>(
        h, t_qkv_w + (size_t)i * 3 * DMODEL * DMODEL, t_qkv_b + i * 3 * DMODEL, bufA,
        DMODEL, DMODEL, 3 * DMODEL);
    // flash attention -> ao (8192 x 512)
    attn_flash<<<1024, 256, 0, stream>>>(bufA, bufB);
    // attn_proj = ao @ ow^T + ob  (8192 x 512, K=512)
    gemm_mfma<0><<<dim3(DMODEL / 128, M / 128), 256, 0, stream>>>(
        bufB, t_ow + (size_t)i * DMODEL * DMODEL, t_ob + i * DMODEL, bufE,
        DMODEL, DMODEL, DMODEL);
    // h = LN(h + attn_proj)
    resid_ln_kernel<<<8192, 128, 0, stream>>>(h, bufE, t_ln1w + i * DMODEL,
                                              t_ln1b + i * DMODEL, h);
    // ff1 = relu(h @ l1w^T + l1b)  (8192 x 2048, K=512)
    gemm_mfma<1><<<dim3(DFF / 128, M / 128), 256, 0, stream>>>(
        h, t_l1w + (size_t)i * DFF * DMODEL, t_l1b + i * DFF, bufA,
        DMODEL, DMODEL, DFF);
    // ff2 = ff1 @ l2w^T + l2b  (8192 x 512, K=2048)
    gemm_mfma<0><<<dim3(DMODEL / 128, M / 128), 256, 0, stream>>>(
        bufA, t_l2w + (size_t)i * DMODEL * DFF, t_l2b + i * DMODEL, bufE,
        DFF, DFF, DMODEL);
    // h = LN(h + ff2)
    resid_ln_kernel<<<8192, 128, 0, stream>>>(h, bufE, t_ln2w + i * DMODEL,
                                              t_ln2b + i * DMODEL, h);
  }

  // final LN -> d_out, then mean over L -> d_out tail
  float* out_h = (float*)d_out;
  resid_ln_kernel<<<8192, 128, 0, stream>>>(h, nullptr, no_w, no_b, out_h);
  mean_kernel<<<16, 256, 0, stream>>>(out_h, out_h + 4194304);
}

// Round 4
// 1441.906 us; speedup vs baseline: 6.6775x; 1.3849x over previous
//
#include <hip/hip_runtime.h>
#include <cstddef>

// Problem constants
#define BATCH 8
#define LSEQ 1024
#define DMODEL 512
#define DINNER 1024
#define DSTATE 16
#define DTRANK 32
#define NHEAD 8
#define DHEAD 64
#define DFF 2048
#define MTOK 8192   // BATCH*LSEQ
#define NCHUNK 16
#define CLEN 64     // LSEQ / NCHUNK

typedef __attribute__((ext_vector_type(8))) short bfrag;   // 8 bf16 (4 VGPRs)
typedef __attribute__((ext_vector_type(4))) float f32x4;   // MFMA acc

__device__ __forceinline__ float silu_f(float x) { return x / (1.f + __expf(-x)); }

__device__ __forceinline__ unsigned short f2bf(float f) {  // RNE fp32->bf16
  unsigned u = __float_as_uint(f);
  return (unsigned short)((u + 0x7FFFu + ((u >> 16) & 1u)) >> 16);
}

// ---------------------------------------------------------------------------
// Input projection: h[b,l,d] = sum_c x[b,c,l] * pw[d,c] + pb[d]
// ---------------------------------------------------------------------------
__global__ __launch_bounds__(256) void proj_kernel(const float* __restrict__ x,
                                                   const float* __restrict__ pw,
                                                   const float* __restrict__ pb,
                                                   float* __restrict__ h) {
  int idx = blockIdx.x * 256 + threadIdx.x;        // ((b*L)+l)*512 + d
  int d = idx & 511;
  int l = (idx >> 9) & 1023;
  int b = idx >> 19;
  const float* xb = x + (size_t)b * 3 * 1024 + l;
  h[idx] = pb[d] + xb[0] * pw[d * 3] + xb[1024] * pw[d * 3 + 1] + xb[2048] * pw[d * 3 + 2];
}

// ---------------------------------------------------------------------------
// bf16 MFMA GEMM: C[m,n] = act( sum_k A[m,k]*W[n,k] + bias[n] )
// A (fp32, lda), W (fp32, ld K) converted RNE->bf16 during LDS staging.
// Tile 128x128, BK=32, 4 waves of 64x64. ACT: 0 none, 1 relu.
// ---------------------------------------------------------------------------
template <int ACT>
__global__ __launch_bounds__(256) void gemm_mfma(const float* __restrict__ A,
                                                 const float* __restrict__ W,
                                                 const float* __restrict__ bias,
                                                 float* __restrict__ C,
                                                 int K, int lda, int ldc) {
  __shared__ bfrag Abuf[512];   // 128 rows x 4 chunks (8 bf16 each), swizzled
  __shared__ bfrag Bbuf[512];
  const int bm = blockIdx.y * 128, bn = blockIdx.x * 128;
  const int tid = threadIdx.x;
  const int wid = tid >> 6, lane = tid & 63;
  const int wr = wid >> 1, wc = wid & 1;
  const int lr = lane & 15, ls = lane >> 4;
  const int sw = ls ^ ((lr >> 1) & 3);            // read-side chunk swizzle

  f32x4 acc[4][4];
#pragma unroll
  for (int i = 0; i < 4; ++i)
#pragma unroll
    for (int j = 0; j < 4; ++j) acc[i][j] = (f32x4)(0.f);

  for (int k0 = 0; k0 < K; k0 += 32) {
    if (k0) __syncthreads();
    // stage A and B tiles (fp32 -> bf16), 512 chunks each, 2 per thread
    for (int c = tid; c < 512; c += 256) {
      int r = c >> 2, s = c & 3;
      int di = (r << 2) + (s ^ ((r >> 1) & 3));
      union { bfrag v; unsigned short u[8]; } pk;
      {
        const float* ap = A + (size_t)(bm + r) * lda + k0 + s * 8;
        float4 f0 = *(const float4*)ap, f1 = *(const float4*)(ap + 4);
        pk.u[0] = f2bf(f0.x); pk.u[1] = f2bf(f0.y); pk.u[2] = f2bf(f0.z); pk.u[3] = f2bf(f0.w);
        pk.u[4] = f2bf(f1.x); pk.u[5] = f2bf(f1.y); pk.u[6] = f2bf(f1.z); pk.u[7] = f2bf(f1.w);
        Abuf[di] = pk.v;
      }
      {
        const float* bp = W + (size_t)(bn + r) * K + k0 + s * 8;
        float4 f0 = *(const float4*)bp, f1 = *(const float4*)(bp + 4);
        pk.u[0] = f2bf(f0.x); pk.u[1] = f2bf(f0.y); pk.u[2] = f2bf(f0.z); pk.u[3] = f2bf(f0.w);
        pk.u[4] = f2bf(f1.x); pk.u[5] = f2bf(f1.y); pk.u[6] = f2bf(f1.z); pk.u[7] = f2bf(f1.w);
        Bbuf[di] = pk.v;
      }
    }
    __syncthreads();

    bfrag af[4], bf[4];
#pragma unroll
    for (int mi = 0; mi < 4; ++mi) {
      int row = wr * 64 + mi * 16 + lr;
      af[mi] = Abuf[(row << 2) + sw];
    }
#pragma unroll
    for (int nj = 0; nj < 4; ++nj) {
      int col = wc * 64 + nj * 16 + lr;
      bf[nj] = Bbuf[(col << 2) + sw];
    }
#pragma unroll
    for (int mi = 0; mi < 4; ++mi)
#pragma unroll
      for (int nj = 0; nj < 4; ++nj)
        acc[mi][nj] = __builtin_amdgcn_mfma_f32_16x16x32_bf16(af[mi], bf[nj], acc[mi][nj], 0, 0, 0);
  }

  // epilogue: C/D layout col=lane&15, row=(lane>>4)*4+reg
#pragma unroll
  for (int nj = 0; nj < 4; ++nj) {
    int col = bn + wc * 64 + nj * 16 + lr;
    float bv = bias ? bias[col] : 0.f;
#pragma unroll
    for (int mi = 0; mi < 4; ++mi) {
      int row0 = bm + wr * 64 + mi * 16 + ls * 4;
#pragma unroll
      for (int r = 0; r < 4; ++r) {
        float v = acc[mi][nj][r] + bv;
        if (ACT == 1) v = fmaxf(v, 0.f);
        C[(size_t)(row0 + r) * ldc + col] = v;
      }
    }
  }
}

// ---------------------------------------------------------------------------
// Generic fp32 tiled SGEMM (kept for small shapes: xproj N=64, dt K=32)
// ACT: 0 none, 2 softplus
// ---------------------------------------------------------------------------
template <int ACT>
__global__ __launch_bounds__(256) void gemm_tn(const float* __restrict__ A,
                                               const float* __restrict__ W,
                                               const float* __restrict__ bias,
                                               float* __restrict__ C,
                                               int M, int N, int K, int lda, int ldc) {
  __shared__ float As[16][65];
  __shared__ float Ws[16][65];
  const int bm = blockIdx.y * 64, bn = blockIdx.x * 64;
  const int tid = threadIdx.x;
  const int lk = tid & 15, lr = tid >> 4;
  const int tx = tid & 15, ty = tid >> 4;
  float acc[4][4] = {};
  for (int k0 = 0; k0 < K; k0 += 16) {
#pragma unroll
    for (int i = 0; i < 4; ++i) {
      As[lk][lr + 16 * i] = A[(size_t)(bm + lr + 16 * i) * lda + k0 + lk];
      Ws[lk][lr + 16 * i] = W[(size_t)(bn + lr + 16 * i) * K + k0 + lk];
    }
    __syncthreads();
#pragma unroll
    for (int kk = 0; kk < 16; ++kk) {
      float a[4], w[4];
#pragma unroll
      for (int i = 0; i < 4; ++i) a[i] = As[kk][ty + 16 * i];
#pragma unroll
      for (int j = 0; j < 4; ++j) w[j] = Ws[kk][tx + 16 * j];
#pragma unroll
      for (int i = 0; i < 4; ++i)
#pragma unroll
        for (int j = 0; j < 4; ++j) acc[i][j] += a[i] * w[j];
    }
    __syncthreads();
  }
#pragma unroll
  for (int i = 0; i < 4; ++i) {
    int r = bm + ty + 16 * i;
#pragma unroll
    for (int j = 0; j < 4; ++j) {
      int c = bn + tx + 16 * j;
      float v = acc[i][j];
      if (bias) v += bias[c];
      if (ACT == 2) v = (v > 20.f) ? v : log1pf(__expf(v));
      C[(size_t)r * ldc + c] = v;
    }
  }
}

// ---------------------------------------------------------------------------
// Depthwise causal conv (width 4) + SiLU.  xm = xz[:, :DINNER] (row stride 2048)
// ---------------------------------------------------------------------------
__global__ __launch_bounds__(256) void conv_silu_kernel(const float* __restrict__ xz,
                                                        const float* __restrict__ cw,
                                                        const float* __restrict__ cb,
                                                        float* __restrict__ xc) {
  int idx = blockIdx.x * 256 + threadIdx.x;        // ((b*L)+t)*1024 + d
  int d = idx & 1023;
  int t = (idx >> 10) & 1023;
  int b = idx >> 20;
  float acc = cb[d];
#pragma unroll
  for (int w = 0; w < 4; ++w) {
    int tt = t - 3 + w;
    if (tt >= 0) acc += xz[(((size_t)(b * 1024 + tt)) << 11) + d] * cw[d * 4 + w];
  }
  xc[idx] = silu_f(acc);
}

// ---------------------------------------------------------------------------
// Chunked selective scan, pass 1: per (b,d,chunk) scan 64 steps with init=0.
// ---------------------------------------------------------------------------
__global__ __launch_bounds__(256) void scan_pass1(const float* __restrict__ dt,
                                                  const float* __restrict__ xdb,
                                                  const float* __restrict__ xc,
                                                  const float* __restrict__ Alog,
                                                  float* __restrict__ scrP,
                                                  float* __restrict__ scrL) {
  int idx = blockIdx.x * 256 + threadIdx.x;        // ((b*16 + c)*1024 + d)
  int d = idx & 1023;
  int c = (idx >> 10) & 15;
  int b = idx >> 14;
  float A[16], st[16], P[16];
#pragma unroll
  for (int s = 0; s < 16; ++s) {
    A[s] = -__expf(Alog[d * 16 + s]);
    st[s] = 0.f;
    P[s] = 1.f;
  }
  int t0 = c * CLEN;
  for (int t = t0; t < t0 + CLEN; ++t) {
    size_t base = (((size_t)(b * 1024 + t)) << 10) + d;
    float dtv = dt[base];
    float xv = xc[base];
    size_t xrow = (size_t)(b * 1024 + t) * 64;
    float dx = dtv * xv;
#pragma unroll
    for (int s = 0; s < 16; ++s) {
      float e = __expf(dtv * A[s]);
      st[s] = st[s] * e + dx * xdb[xrow + 32 + s];
      P[s] *= e;
    }
  }
  size_t pbase = (((size_t)((b * 16 + c) * 16)) << 10) + d;
#pragma unroll
  for (int s = 0; s < 16; ++s) {
    scrP[pbase + ((size_t)s << 10)] = P[s];
    scrL[pbase + ((size_t)s << 10)] = st[s];
  }
}

// ---------------------------------------------------------------------------
// Pass 2: combine chunks serially per (b,d,s).
// ---------------------------------------------------------------------------
__global__ __launch_bounds__(256) void scan_pass2(const float* __restrict__ scrP,
                                                  float* __restrict__ scrL) {
  int idx = blockIdx.x * 256 + threadIdx.x;        // ((b*16 + s)*1024 + d)
  int d = idx & 1023;
  int s = (idx >> 10) & 15;
  int b = idx >> 14;
  float cur = 0.f;
  for (int c = 0; c < 16; ++c) {
    size_t o = (((size_t)(((b * 16 + c) * 16) + s)) << 10) + d;
    float P = scrP[o];
    float loc = scrL[o];
    scrL[o] = cur;
    cur = cur * P + loc;
  }
}

// ---------------------------------------------------------------------------
// Pass 3: rescan each chunk with correct init, produce gated y into xz[:, :1024].
// ---------------------------------------------------------------------------
__global__ __launch_bounds__(256) void scan_pass3(const float* __restrict__ dt,
                                                  const float* __restrict__ xdb,
                                                  const float* __restrict__ xc,
                                                  float* __restrict__ xz,
                                                  const float* __restrict__ Alog,
                                                  const float* __restrict__ Dp,
                                                  const float* __restrict__ scrL) {
  int idx = blockIdx.x * 256 + threadIdx.x;        // ((b*16 + c)*1024 + d)
  int d = idx & 1023;
  int c = (idx >> 10) & 15;
  int b = idx >> 14;
  float A[16], st[16];
  size_t pbase = (((size_t)((b * 16 + c) * 16)) << 10) + d;
#pragma unroll
  for (int s = 0; s < 16; ++s) {
    A[s] = -__expf(Alog[d * 16 + s]);
    st[s] = scrL[pbase + ((size_t)s << 10)];
  }
  float Dv = Dp[d];
  int t0 = c * CLEN;
  for (int t = t0; t < t0 + CLEN; ++t) {
    size_t base = (((size_t)(b * 1024 + t)) << 10) + d;
    float dtv = dt[base];
    float xv = xc[base];
    size_t xrow = (size_t)(b * 1024 + t) * 64;
    float dx = dtv * xv;
    float acc = 0.f;
#pragma unroll
    for (int s = 0; s < 16; ++s) {
      float e = __expf(dtv * A[s]);
      st[s] = st[s] * e + dx * xdb[xrow + 32 + s];
      acc += st[s] * xdb[xrow + 48 + s];
    }
    size_t zrow = ((size_t)(b * 1024 + t)) << 11;
    float zv = xz[zrow + 1024 + d];
    xz[zrow + d] = (acc + Dv * xv) * silu_f(zv);
  }
}

// ---------------------------------------------------------------------------
// Residual + LayerNorm (in-place capable). add may be nullptr.
// ---------------------------------------------------------------------------
__global__ __launch_bounds__(128) void resid_ln_kernel(const float* __restrict__ x,
                                                       const float* __restrict__ add,
                                                       const float* __restrict__ w,
                                                       const float* __restrict__ bias,
                                                       float* __restrict__ out) {
  int row = blockIdx.x, tid = threadIdx.x;
  float4 v = ((const float4*)(x + (size_t)row * 512))[tid];
  if (add) {
    float4 a = ((const float4*)(add + (size_t)row * 512))[tid];
    v.x += a.x; v.y += a.y; v.z += a.z; v.w += a.w;
  }
  float s = v.x + v.y + v.z + v.w;
  float ss = v.x * v.x + v.y * v.y + v.z * v.z + v.w * v.w;
#pragma unroll
  for (int o = 32; o; o >>= 1) {
    s += __shfl_xor(s, o);
    ss += __shfl_xor(ss, o);
  }
  __shared__ float red[4];
  int wid = tid >> 6;
  if ((tid & 63) == 0) { red[wid] = s; red[2 + wid] = ss; }
  __syncthreads();
  s = red[0] + red[1];
  ss = red[2] + red[3];
  float mean = s * (1.f / 512.f);
  float var = ss * (1.f / 512.f) - mean * mean;
  float inv = rsqrtf(var + 1e-5f);
  float4 wv = ((const float4*)w)[tid];
  float4 bv = ((const float4*)bias)[tid];
  float4 ov;
  ov.x = (v.x - mean) * inv * wv.x + bv.x;
  ov.y = (v.y - mean) * inv * wv.y + bv.y;
  ov.z = (v.z - mean) * inv * wv.z + bv.z;
  ov.w = (v.w - mean) * inv * wv.w + bv.w;
  ((float4*)(out + (size_t)row * 512))[tid] = ov;
}

// ---------------------------------------------------------------------------
// Sinusoidal positional encoding add (in-place on h)
// ---------------------------------------------------------------------------
__global__ __launch_bounds__(256) void posenc_kernel(float* __restrict__ h) {
  int idx = blockIdx.x * 256 + threadIdx.x;
  int d = idx & 511;
  int l = (idx >> 9) & 1023;
  float freq = __expf(-(float)(d & ~1) * (9.210340371976184f / 512.f));
  float ang = (float)l * freq;
  h[idx] += (d & 1) ? cosf(ang) : sinf(ang);
}

// ---------------------------------------------------------------------------
// MFMA flash attention. One block = (b, head, 64 q-rows); 4 waves x 16 q-rows.
// LDS bf16 tiles, chunk-XOR swizzle: elem (row,col) at
//   row*64 + (((col>>3) ^ (row&7))<<3) + (col&7)   [bf16 units]
// Q,K row-major (row=seq, col=d); V transposed (row=d, col=kv);
// P per-wave private 16x64 region. All fragment reads are ds_read_b128, <=2-way.
// ---------------------------------------------------------------------------
__global__ __launch_bounds__(256) void attn_mfma(const float* __restrict__ qkv,
                                                 float* __restrict__ ao) {
  __shared__ unsigned short Qs[4096];
  __shared__ unsigned short Ks[4096];
  __shared__ unsigned short Vt[4096];
  __shared__ unsigned short Ps[4096];
  const int tid = threadIdx.x;
  const int blk = blockIdx.x;                    // ((b*8 + h)*16 + qt)
  const int qt = blk & 15, hh = (blk >> 4) & 7, b = blk >> 7;
  const int l0 = qt * 64;
  const size_t bb = (size_t)b * 1024 * 1536;

  const int srow = tid >> 2;                     // staging: row 0..63
  const int sdb = (tid & 3) << 4;                // staging: d-block 0/16/32/48
  const int sc0 = sdb >> 3;                      // first chunk index

  // stage Q (scaled), row-major swizzled
  {
    const float* qp = qkv + bb + (size_t)(l0 + srow) * 1536 + hh * 64 + sdb;
    union { bfrag v; unsigned short u[8]; } c0, c1;
    float4 f0 = *(const float4*)qp, f1 = *(const float4*)(qp + 4);
    float4 f2 = *(const float4*)(qp + 8), f3 = *(const float4*)(qp + 12);
    c0.u[0]=f2bf(f0.x*0.125f); c0.u[1]=f2bf(f0.y*0.125f); c0.u[2]=f2bf(f0.z*0.125f); c0.u[3]=f2bf(f0.w*0.125f);
    c0.u[4]=f2bf(f1.x*0.125f); c0.u[5]=f2bf(f1.y*0.125f); c0.u[6]=f2bf(f1.z*0.125f); c0.u[7]=f2bf(f1.w*0.125f);
    c1.u[0]=f2bf(f2.x*0.125f); c1.u[1]=f2bf(f2.y*0.125f); c1.u[2]=f2bf(f2.z*0.125f); c1.u[3]=f2bf(f2.w*0.125f);
    c1.u[4]=f2bf(f3.x*0.125f); c1.u[5]=f2bf(f3.y*0.125f); c1.u[6]=f2bf(f3.z*0.125f); c1.u[7]=f2bf(f3.w*0.125f);
    *(bfrag*)&Qs[srow * 64 + ((sc0 ^ (srow & 7)) << 3)] = c0.v;
    *(bfrag*)&Qs[srow * 64 + (((sc0 + 1) ^ (srow & 7)) << 3)] = c1.v;
  }

  const int wid = tid >> 6, lane = tid & 63;
  const int l15 = lane & 15, rg = lane >> 4;
  const int l7 = l15 & 7;
  float m[4], lsum[4];
  f32x4 oacc[4];
#pragma unroll
  for (int r = 0; r < 4; ++r) { m[r] = -1e30f; lsum[r] = 0.f; }
#pragma unroll
  for (int nt = 0; nt < 4; ++nt) oacc[nt] = (f32x4)(0.f);

  for (int jt = 0; jt < 16; ++jt) {
    // ---- stage K (row-major) and V (transposed), bf16 swizzled ----
    {
      const float* kp = qkv + bb + (size_t)(jt * 64 + srow) * 1536 + hh * 64 + 512 + sdb;
      union { bfrag v; unsigned short u[8]; } c0, c1;
      float4 f0 = *(const float4*)kp, f1 = *(const float4*)(kp + 4);
      float4 f2 = *(const float4*)(kp + 8), f3 = *(const float4*)(kp + 12);
      c0.u[0]=f2bf(f0.x); c0.u[1]=f2bf(f0.y); c0.u[2]=f2bf(f0.z); c0.u[3]=f2bf(f0.w);
      c0.u[4]=f2bf(f1.x); c0.u[5]=f2bf(f1.y); c0.u[6]=f2bf(f1.z); c0.u[7]=f2bf(f1.w);
      c1.u[0]=f2bf(f2.x); c1.u[1]=f2bf(f2.y); c1.u[2]=f2bf(f2.z); c1.u[3]=f2bf(f2.w);
      c1.u[4]=f2bf(f3.x); c1.u[5]=f2bf(f3.y); c1.u[6]=f2bf(f3.z); c1.u[7]=f2bf(f3.w);
      *(bfrag*)&Ks[srow * 64 + ((sc0 ^ (srow & 7)) << 3)] = c0.v;
      *(bfrag*)&Ks[srow * 64 + (((sc0 + 1) ^ (srow & 7)) << 3)] = c1.v;
      // V: transpose into Vt[d][kv]
      const float* vp = kp + 512;
      float vf[16];
      *(float4*)&vf[0] = *(const float4*)vp;       *(float4*)&vf[4] = *(const float4*)(vp + 4);
      *(float4*)&vf[8] = *(const float4*)(vp + 8); *(float4*)&vf[12] = *(const float4*)(vp + 12);
#pragma unroll
      for (int j = 0; j < 16; ++j) {
        int dd = sdb + j;
        Vt[dd * 64 + (((srow >> 3) ^ (dd & 7)) << 3) + (srow & 7)] = f2bf(vf[j]);
      }
    }
    __syncthreads();

    // ---- S = Q K^T : per wave 16 q-rows x 64 kv-cols ----
    bfrag aq[2];
#pragma unroll
    for (int ks = 0; ks < 2; ++ks)
      aq[ks] = *(const bfrag*)&Qs[(wid * 16 + l15) * 64 + (((ks * 4 + rg) ^ l7) << 3)];
    f32x4 sc[4];
#pragma unroll
    for (int nt = 0; nt < 4; ++nt) {
      f32x4 s = (f32x4)(0.f);
#pragma unroll
      for (int ks = 0; ks < 2; ++ks) {
        bfrag bk = *(const bfrag*)&Ks[(nt * 16 + l15) * 64 + (((ks * 4 + rg) ^ l7) << 3)];
        s = __builtin_amdgcn_mfma_f32_16x16x32_bf16(aq[ks], bk, s, 0, 0, 0);
      }
      sc[nt] = s;
    }

    // ---- online softmax; P -> bf16 LDS (per-wave region, same-wave r/w) ----
#pragma unroll
    for (int r = 0; r < 4; ++r) {
      float mc = fmaxf(fmaxf(sc[0][r], sc[1][r]), fmaxf(sc[2][r], sc[3][r]));
#pragma unroll
      for (int o = 8; o; o >>= 1) mc = fmaxf(mc, __shfl_xor(mc, o));
      float mn = fmaxf(m[r], mc);
      float al = __expf(m[r] - mn);
      m[r] = mn;
      int prow = rg * 4 + r;
      float ps = 0.f;
#pragma unroll
      for (int nt = 0; nt < 4; ++nt) {
        float p = __expf(sc[nt][r] - mn);
        ps += p;
        int col = nt * 16 + l15;
        Ps[wid * 1024 + prow * 64 + ((((col >> 3) ^ (prow & 7))) << 3) + (col & 7)] = f2bf(p);
      }
#pragma unroll
      for (int o = 8; o; o >>= 1) ps += __shfl_xor(ps, o);
      lsum[r] = lsum[r] * al + ps;
#pragma unroll
      for (int nt = 0; nt < 4; ++nt) oacc[nt][r] *= al;
    }

    // ---- O += P V  (A=P rows q, k=kv; B=Vt col d, k=kv) ----
    bfrag ap[2];
#pragma unroll
    for (int ks = 0; ks < 2; ++ks)
      ap[ks] = *(const bfrag*)&Ps[wid * 1024 + l15 * 64 + (((ks * 4 + rg) ^ l7) << 3)];
#pragma unroll
    for (int nt = 0; nt < 4; ++nt) {
#pragma unroll
      for (int ks = 0; ks < 2; ++ks) {
        bfrag bv = *(const bfrag*)&Vt[(nt * 16 + l15) * 64 + (((ks * 4 + rg) ^ l7) << 3)];
        oacc[nt] = __builtin_amdgcn_mfma_f32_16x16x32_bf16(ap[ks], bv, oacc[nt], 0, 0, 0);
      }
    }
    __syncthreads();
  }

  // ---- epilogue: O /= lsum, write ----
#pragma unroll
  for (int r = 0; r < 4; ++r) {
    float inv = 1.f / lsum[r];
    int row = l0 + wid * 16 + rg * 4 + r;
    float* op = ao + ((size_t)(b * 1024 + row)) * 512 + hh * 64;
#pragma unroll
    for (int nt = 0; nt < 4; ++nt) op[nt * 16 + l15] = oacc[nt][r] * inv;
  }
}

// ---------------------------------------------------------------------------
// Mean over L: out2[b,d] = mean_l hout[b,l,d]
// ---------------------------------------------------------------------------
__global__ __launch_bounds__(256) void mean_kernel(const float* __restrict__ hout,
                                                   float* __restrict__ out2) {
  int idx = blockIdx.x * 256 + threadIdx.x;
  int b = idx >> 9, d = idx & 511;
  float s = 0.f;
  for (int l = 0; l < 1024; ++l) s += hout[(((size_t)(b * 1024 + l)) << 9) + d];
  out2[idx] = s * (1.f / 1024.f);
}

// ---------------------------------------------------------------------------
extern "C" void kernel_launch(void* const* d_in, const int* in_sizes, int n_in,
                              void* d_out, int out_size, void* d_ws, size_t ws_size,
                              hipStream_t stream) {
  const float* x        = (const float*)d_in[0];
  const float* proj_w   = (const float*)d_in[1];
  const float* proj_b   = (const float*)d_in[2];
  const float* m_in_w   = (const float*)d_in[3];
  const float* m_conv_w = (const float*)d_in[4];
  const float* m_conv_b = (const float*)d_in[5];
  const float* m_xproj_w= (const float*)d_in[6];
  const float* m_dt_w   = (const float*)d_in[7];
  const float* m_dt_b   = (const float*)d_in[8];
  const float* m_Alog   = (const float*)d_in[9];
  const float* m_D      = (const float*)d_in[10];
  const float* m_out_w  = (const float*)d_in[11];
  const float* m_ln_w   = (const float*)d_in[12];
  const float* m_ln_b   = (const float*)d_in[13];
  const float* t_qkv_w  = (const float*)d_in[14];
  const float* t_qkv_b  = (const float*)d_in[15];
  const float* t_ow     = (const float*)d_in[16];
  const float* t_ob     = (const float*)d_in[17];
  const float* t_l1w    = (const float*)d_in[18];
  const float* t_l1b    = (const float*)d_in[19];
  const float* t_l2w    = (const float*)d_in[20];
  const float* t_l2b    = (const float*)d_in[21];
  const float* t_ln1w   = (const float*)d_in[22];
  const float* t_ln1b   = (const float*)d_in[23];
  const float* t_ln2w   = (const float*)d_in[24];
  const float* t_ln2b   = (const float*)d_in[25];
  const float* no_w     = (const float*)d_in[26];
  const float* no_b     = (const float*)d_in[27];

  float* ws   = (float*)d_ws;
  float* h    = ws;                   //  4,194,304 f  (B,L,512)
  float* bufA = h + 4194304;          // 16,777,216 f  (xz / qkv / ff1)
  float* bufB = bufA + 16777216;      //  8,388,608 f  (xc / ao)
  float* bufC = bufB + 8388608;       //  8,388,608 f  (dt)
  float* bufE = bufC + 8388608;       //  4,194,304 f  (scan scratch / mamba-out / attn-proj / ff2)
  float* bufF = bufE + 4194304;       //    524,288 f  (xdb)
  float* scrP = bufE;                 //  2,097,152 f  (chunk decay products)
  float* scrL = bufE + 2097152;       //  2,097,152 f  (chunk local-end -> init states)
  const int M = MTOK;

  proj_kernel<<<16384, 256, 0, stream>>>(x, proj_w, proj_b, h);

  for (int i = 0; i < 2; ++i) {
    // xz = h @ in_w^T   (8192 x 2048, K=512)
    gemm_mfma<0><<<dim3(2 * DINNER / 128, M / 128), 256, 0, stream>>>(
        h, m_in_w + (size_t)i * 2 * DINNER * DMODEL, nullptr, bufA,
        DMODEL, DMODEL, 2 * DINNER);
    // xc = silu(causal_conv(xm))
    conv_silu_kernel<<<32768, 256, 0, stream>>>(bufA, m_conv_w + i * DINNER * 4,
                                                m_conv_b + i * DINNER, bufB);
    // xdb = xc @ xp_w^T  (8192 x 64, K=1024) — small N, fp32
    gemm_tn<0><<<dim3(1, M / 64), 256, 0, stream>>>(
        bufB, m_xproj_w + (size_t)i * 64 * DINNER, nullptr, bufF,
        M, 64, DINNER, DINNER, 64);
    // dt = softplus(xdb[:, :32] @ dt_w^T + dt_b)  (8192 x 1024, K=32) — fp32
    gemm_tn<2><<<dim3(DINNER / 64, M / 64), 256, 0, stream>>>(
        bufF, m_dt_w + (size_t)i * DINNER * DTRANK, m_dt_b + i * DINNER, bufC,
        M, DINNER, DTRANK, 64, DINNER);
    // chunked selective scan -> gated y written into xz[:, :1024] slots
    scan_pass1<<<512, 256, 0, stream>>>(bufC, bufF, bufB,
                                        m_Alog + (size_t)i * DINNER * DSTATE, scrP, scrL);
    scan_pass2<<<512, 256, 0, stream>>>(scrP, scrL);
    scan_pass3<<<512, 256, 0, stream>>>(bufC, bufF, bufB, bufA,
                                        m_Alog + (size_t)i * DINNER * DSTATE,
                                        m_D + i * DINNER, scrL);
    // mamba_out = y @ out_w^T  (8192 x 512, K=1024, lda=2048)
    gemm_mfma<0><<<dim3(DMODEL / 128, M / 128), 256, 0, stream>>>(
        bufA, m_out_w + (size_t)i * DMODEL * DINNER, nullptr, bufE,
        DINNER, 2 * DINNER, DMODEL);
    // h = LN(h + mamba_out)
    resid_ln_kernel<<<8192, 128, 0, stream>>>(h, bufE, m_ln_w + i * DMODEL,
                                              m_ln_b + i * DMODEL, h);
  }

  posenc_kernel<<<16384, 256, 0, stream>>>(h);

  for (int i = 0; i < 2; ++i) {
    // qkv = h @ qkv_w^T + qkv_b  (8192 x 1536, K=512)
    gemm_mfma<0><<<dim3(3 * DMODEL / 128, M / 128), 256, 0, stream>>>(
        h, t_qkv_w + (size_t)i * 3 * DMODEL * DMODEL, t_qkv_b + i * 3 * DMODEL, bufA,
        DMODEL, DMODEL, 3 * DMODEL);
    // MFMA flash attention -> ao (8192 x 512)
    attn_mfma<<<1024, 256, 0, stream>>>(bufA, bufB);
    // attn_proj = ao @ ow^T + ob  (8192 x 512, K=512)
    gemm_mfma<0><<<dim3(DMODEL / 128, M / 128), 256, 0, stream>>>(
        bufB, t_ow + (size_t)i * DMODEL * DMODEL, t_ob + i * DMODEL, bufE,
        DMODEL, DMODEL, DMODEL);
    // h = LN(h + attn_proj)
    resid_ln_kernel<<<8192, 128, 0, stream>>>(h, bufE, t_ln1w + i * DMODEL,
                                              t_ln1b + i * DMODEL, h);
    // ff1 = relu(h @ l1w^T + l1b)  (8192 x 2048, K=512)
    gemm_mfma<1><<<dim3(DFF / 128, M / 128), 256, 0, stream>>>(
        h, t_l1w + (size_t)i * DFF * DMODEL, t_l1b + i * DFF, bufA,
        DMODEL, DMODEL, DFF);
    // ff2 = ff1 @ l2w^T + l2b  (8192 x 512, K=2048)
    gemm_mfma<0><<<dim3(DMODEL / 128, M / 128), 256, 0, stream>>>(
        bufA, t_l2w + (size_t)i * DMODEL * DFF, t_l2b + i * DMODEL, bufE,
        DFF, DFF, DMODEL);
    // h = LN(h + ff2)
    resid_ln_kernel<<<8192, 128, 0, stream>>>(h, bufE, t_ln2w + i * DMODEL,
                                              t_ln2b + i * DMODEL, h);
  }

  // final LN -> d_out, then mean over L -> d_out tail
  float* out_h = (float*)d_out;
  resid_ln_kernel<<<8192, 128, 0, stream>>>(h, nullptr, no_w, no_b, out_h);
  mean_kernel<<<16, 256, 0, stream>>>(out_h, out_h + 4194304);
}